// Round 11
// baseline (267.606 us; speedup 1.0000x reference)
//
#include <hip/hip_runtime.h>

// GAT 2-layer. N=50000, E=1.6M (deg 32). L1: 256->8x32 (bf16 MFMA).
// CSR build: cap-strided counting sort (part: LDS hist + atomic-return per
// (block,bucket) -> bscan -> build). No per-edge global atomics, no bcount.
// gemm1m epilogue fuses el/er. agg1: wave-per-node, batched gathers +
// group prefetch, fused h@W2 -> node4.

#define NN 50000
#define NE 1600000
#define NBK 196      // coarse buckets of 256 nodes
#define PCH 6250     // edges per partition block; 256 * 6250 = NE
#define CAP 16384    // stage capacity per bucket (mean 8192, sigma ~90)

typedef __attribute__((ext_vector_type(8))) short short8;
typedef __attribute__((ext_vector_type(4))) float f32x4;

__device__ inline unsigned short f2bf(float f) {
  unsigned int u = __float_as_uint(f);
  unsigned int r = (u + 0x7fffu + ((u >> 16) & 1u)) >> 16;
  return (unsigned short)r;
}
__device__ inline float bf2f(unsigned short h) {
  return __uint_as_float(((unsigned int)h) << 16);
}
__device__ inline float lrelu_exp(float v) {
  v = v >= 0.f ? v : 0.2f * v;
  return __expf(v);
}

// partition edges into cap-strided bucket regions; one atomic-return per
// (block,bucket); writes ~256B sequential chunks per bucket run.
__global__ __launch_bounds__(256) void k_part(const int* __restrict__ dst,
                                              const int* __restrict__ src,
                                              int* __restrict__ cur,
                                              int2* __restrict__ stage, int E) {
  __shared__ int h[NBK], base[NBK], lofs[NBK];
  int tid = threadIdx.x;
  for (int i = tid; i < NBK; i += 256) h[i] = 0;
  __syncthreads();
  int b0 = blockIdx.x * PCH;
  for (int k = tid; k < PCH; k += 256) {
    int i = b0 + k;
    if (i < E) atomicAdd(&h[dst[i] >> 8], 1);
  }
  __syncthreads();
  for (int i = tid; i < NBK; i += 256) {
    base[i] = h[i] ? atomicAdd(&cur[i], h[i]) : 0;
    lofs[i] = 0;
  }
  __syncthreads();
  for (int k = tid; k < PCH; k += 256) {
    int i = b0 + k;
    if (i < E) {
      int d = dst[i];
      int b = d >> 8;
      int r = atomicAdd(&lofs[b], 1);
      stage[(size_t)b * CAP + base[b] + r] = make_int2(d, src[i]);
    }
  }
}

// scan bucket totals (=cur) -> bbase[0..NBK].
__global__ __launch_bounds__(256) void k_bscan(const int* __restrict__ cur,
                                               int* __restrict__ bbase) {
  __shared__ int buf[256];
  int tid = threadIdx.x;
  int v = (tid < NBK) ? cur[tid] : 0;
  buf[tid] = v;
  __syncthreads();
  for (int off = 1; off < 256; off <<= 1) {
    int t = (tid >= off) ? buf[tid - off] : 0;
    __syncthreads();
    buf[tid] += t;
    __syncthreads();
  }
  if (tid < NBK) bbase[tid] = buf[tid] - v;
  if (tid == NBK - 1) bbase[NBK] = buf[tid];
}

// per-bucket (256 nodes) LDS counting sort: writes offs slice + places csr.
__global__ __launch_bounds__(256) void k_build(const int2* __restrict__ stage,
                                               const int* __restrict__ bbase,
                                               int* __restrict__ offs,
                                               int* __restrict__ csr, int n,
                                               int E) {
  __shared__ int h[256], buf[256], cur[256];
  int b = blockIdx.x, tid = threadIdx.x;
  int beg = bbase[b];
  int tot = bbase[b + 1] - beg;
  const int2* st = stage + (size_t)b * CAP;
  h[tid] = 0;
  __syncthreads();
  for (int k = tid; k < tot; k += 256)
    atomicAdd(&h[st[k].x & 255], 1);
  __syncthreads();
  int v = h[tid];
  buf[tid] = v;
  __syncthreads();
  for (int off = 1; off < 256; off <<= 1) {
    int t = (tid >= off) ? buf[tid - off] : 0;
    __syncthreads();
    buf[tid] += t;
    __syncthreads();
  }
  int excl = buf[tid] - v;
  int node = b * 256 + tid;
  if (node < n) offs[node] = beg + excl;
  if (b == 0 && tid == 0) offs[n] = E;
  cur[tid] = excl;
  __syncthreads();
  for (int k = tid; k < tot; k += 256) {
    int2 e = st[k];
    int r = atomicAdd(&cur[e.x & 255], 1);
    csr[beg + r] = e.y;
  }
}

// Pack W1 (256x256 f32 row-major [k][n]) into MFMA B-fragment order, bf16.
__global__ __launch_bounds__(256) void k_packw(const float* __restrict__ W1,
                                               unsigned short* __restrict__ W1p) {
  int idx = blockIdx.x * 256 + threadIdx.x;  // 8192 total
  int nf = idx >> 9, rem = idx & 511;
  int ks = rem >> 6, lane = rem & 63;
  int n = nf * 16 + (lane & 15);
  int kb = ks * 32 + (lane >> 4) * 8;
#pragma unroll
  for (int j = 0; j < 8; ++j)
    W1p[(size_t)idx * 8 + j] = f2bf(W1[(kb + j) * 256 + n]);
}

// MFMA GEMM: feat_bf16 = bf16(x) @ bf16(W1), fused el/er epilogue.
// Lane (r0=l&15,kgrp=l>>4) holds D cols nf*16+r0 (head nf>>1), rows
// tile+mf*16+kgrp*4+q. el[row][h]=sum over 16-lane r0 group of
// acc[2h]*al[32h+r0]+acc[2h+1]*al[32h+16+r0].
__global__ __launch_bounds__(256) void k_gemm1m(
    const float* __restrict__ x, const unsigned short* __restrict__ W1p,
    const float* __restrict__ al, const float* __restrict__ ar,
    unsigned short* __restrict__ featb, float* __restrict__ el,
    float* __restrict__ er, int n) {
  int w = threadIdx.x >> 6, lane = threadIdx.x & 63;
  int tile = (blockIdx.x * 4 + w) * 32;
  if (tile >= n) return;
  int r0 = lane & 15, kgrp = lane >> 4;
  f32x4 acc[16][2];
#pragma unroll
  for (int nf = 0; nf < 16; ++nf)
#pragma unroll
    for (int mf = 0; mf < 2; ++mf) acc[nf][mf] = (f32x4){0.f, 0.f, 0.f, 0.f};

  for (int ks = 0; ks < 8; ++ks) {
    int kb = ks * 32 + kgrp * 8;
    short8 a0, a1;
    {
      int row = tile + r0;
      const float* p = x + (size_t)row * 256 + kb;
      float4 v0 = *reinterpret_cast<const float4*>(p);
      float4 v1 = *reinterpret_cast<const float4*>(p + 4);
      a0[0] = (short)f2bf(v0.x); a0[1] = (short)f2bf(v0.y);
      a0[2] = (short)f2bf(v0.z); a0[3] = (short)f2bf(v0.w);
      a0[4] = (short)f2bf(v1.x); a0[5] = (short)f2bf(v1.y);
      a0[6] = (short)f2bf(v1.z); a0[7] = (short)f2bf(v1.w);
    }
    {
      int row = tile + 16 + r0;
      if (row < n) {
        const float* p = x + (size_t)row * 256 + kb;
        float4 v0 = *reinterpret_cast<const float4*>(p);
        float4 v1 = *reinterpret_cast<const float4*>(p + 4);
        a1[0] = (short)f2bf(v0.x); a1[1] = (short)f2bf(v0.y);
        a1[2] = (short)f2bf(v0.z); a1[3] = (short)f2bf(v0.w);
        a1[4] = (short)f2bf(v1.x); a1[5] = (short)f2bf(v1.y);
        a1[6] = (short)f2bf(v1.z); a1[7] = (short)f2bf(v1.w);
      } else {
#pragma unroll
        for (int j = 0; j < 8; ++j) a1[j] = 0;
      }
    }
#pragma unroll
    for (int nf = 0; nf < 16; ++nf) {
      short8 b = *reinterpret_cast<const short8*>(
          W1p + ((size_t)(nf * 8 + ks) * 64 + lane) * 8);
      acc[nf][0] = __builtin_amdgcn_mfma_f32_16x16x32_bf16(a0, b, acc[nf][0], 0, 0, 0);
      acc[nf][1] = __builtin_amdgcn_mfma_f32_16x16x32_bf16(a1, b, acc[nf][1], 0, 0, 0);
    }
  }
  // store feat bf16
#pragma unroll
  for (int nf = 0; nf < 16; ++nf)
#pragma unroll
    for (int mf = 0; mf < 2; ++mf)
#pragma unroll
      for (int q = 0; q < 4; ++q) {
        int row = tile + mf * 16 + kgrp * 4 + q;
        if (row < n)
          featb[(size_t)row * 256 + nf * 16 + r0] = f2bf(acc[nf][mf][q]);
      }
  // fused el/er
  float alv[16], arv[16];
#pragma unroll
  for (int nf = 0; nf < 16; ++nf) {
    alv[nf] = al[nf * 16 + r0];
    arv[nf] = ar[nf * 16 + r0];
  }
#pragma unroll
  for (int mf = 0; mf < 2; ++mf) {
    float elp[4][8], erp[4][8];
#pragma unroll
    for (int q = 0; q < 4; ++q)
#pragma unroll
      for (int h = 0; h < 8; ++h) {
        elp[q][h] = acc[2 * h][mf][q] * alv[2 * h] +
                    acc[2 * h + 1][mf][q] * alv[2 * h + 1];
        erp[q][h] = acc[2 * h][mf][q] * arv[2 * h] +
                    acc[2 * h + 1][mf][q] * arv[2 * h + 1];
      }
#pragma unroll
    for (int st = 1; st < 16; st <<= 1)
#pragma unroll
      for (int q = 0; q < 4; ++q)
#pragma unroll
        for (int h = 0; h < 8; ++h) {
          elp[q][h] += __shfl_xor(elp[q][h], st, 64);
          erp[q][h] += __shfl_xor(erp[q][h], st, 64);
        }
    if (r0 == 0) {
#pragma unroll
      for (int q = 0; q < 4; ++q) {
        int row = tile + mf * 16 + kgrp * 4 + q;
        if (row < n) {
          float4 e0 = {elp[q][0], elp[q][1], elp[q][2], elp[q][3]};
          float4 e1 = {elp[q][4], elp[q][5], elp[q][6], elp[q][7]};
          float4 r0v = {erp[q][0], erp[q][1], erp[q][2], erp[q][3]};
          float4 r1v = {erp[q][4], erp[q][5], erp[q][6], erp[q][7]};
          *reinterpret_cast<float4*>(el + (size_t)row * 8) = e0;
          *reinterpret_cast<float4*>(el + (size_t)row * 8 + 4) = e1;
          *reinterpret_cast<float4*>(er + (size_t)row * 8) = r0v;
          *reinterpret_cast<float4*>(er + (size_t)row * 8 + 4) = r1v;
        }
      }
    }
  }
}

// Wave per dst node. Lane l owns cols l*4..l*4+3 (head hh=l>>3).
// 8-edge groups: batch-issue 8 gathers, prefetch next group's csr/el/exp.
__global__ __launch_bounds__(256) void k_agg1(
    const unsigned short* __restrict__ featb, const float* __restrict__ el,
    const float* __restrict__ er, const int* __restrict__ offs,
    const int* __restrict__ csr, const float* __restrict__ b1,
    const float* __restrict__ W2, const float* __restrict__ al2,
    const float* __restrict__ ar2, float4* __restrict__ node4, int n) {
  int dn = blockIdx.x * 4 + (threadIdx.x >> 6);
  if (dn >= n) return;
  int l = threadIdx.x & 63;
  int hh = l >> 3;  // head of this lane's 4 output cols
  int h8 = l & 7;   // head for ee computation
  int e8 = l >> 3;  // edge slot for csr/el loads
  float erv = er[dn * 8 + h8];
  int beg = offs[dn], end = offs[dn + 1];
  float4 acc = {0.f, 0.f, 0.f, 0.f};
  float den = 0.f;
  int g = beg;
  int s_my = 0;
  float eev = 0.f;
  if (g + 8 <= end) {
    s_my = csr[g + e8];
    eev = lrelu_exp(el[s_my * 8 + h8] + erv);
  }
  for (; g + 8 <= end; g += 8) {
    int ss[8];
#pragma unroll
    for (int e = 0; e < 8; ++e) ss[e] = __shfl(s_my, e * 8, 64);
    ushort4 fv[8];
#pragma unroll
    for (int e = 0; e < 8; ++e)
      fv[e] = *reinterpret_cast<const ushort4*>(featb + (size_t)ss[e] * 256 + l * 4);
    float ees[8];
#pragma unroll
    for (int e = 0; e < 8; ++e) ees[e] = __shfl(eev, e * 8 + hh, 64);
    if (g + 16 <= end) {  // prefetch next group while gathers are in flight
      s_my = csr[g + 8 + e8];
      eev = lrelu_exp(el[s_my * 8 + h8] + erv);
    }
#pragma unroll
    for (int e = 0; e < 8; ++e) {
      den += ees[e];
      acc.x = fmaf(ees[e], bf2f(fv[e].x), acc.x);
      acc.y = fmaf(ees[e], bf2f(fv[e].y), acc.y);
      acc.z = fmaf(ees[e], bf2f(fv[e].z), acc.z);
      acc.w = fmaf(ees[e], bf2f(fv[e].w), acc.w);
    }
  }
  if (g < end) {
    int rem = end - g;
    int idx = g + e8;
    int s_t = csr[idx < end ? idx : end - 1];
    float ee_t = lrelu_exp(el[s_t * 8 + h8] + erv);
    for (int e = 0; e < rem; ++e) {
      int s = __shfl(s_t, e * 8, 64);
      float ee = __shfl(ee_t, e * 8 + hh, 64);
      den += ee;
      ushort4 fv = *reinterpret_cast<const ushort4*>(featb + (size_t)s * 256 + l * 4);
      acc.x = fmaf(ee, bf2f(fv.x), acc.x);
      acc.y = fmaf(ee, bf2f(fv.y), acc.y);
      acc.z = fmaf(ee, bf2f(fv.z), acc.z);
      acc.w = fmaf(ee, bf2f(fv.w), acc.w);
    }
  }
  float4 bv = *reinterpret_cast<const float4*>(b1 + l * 4);
  float4 w2e = *reinterpret_cast<const float4*>(W2 + l * 8);
  float4 w2o = *reinterpret_cast<const float4*>(W2 + l * 8 + 4);
  float inv = 1.f / fmaxf(den, 1e-16f);
  float v0 = acc.x * inv + bv.x; v0 = v0 > 0.f ? v0 : expm1f(v0);
  float v1 = acc.y * inv + bv.y; v1 = v1 > 0.f ? v1 : expm1f(v1);
  float v2 = acc.z * inv + bv.z; v2 = v2 > 0.f ? v2 : expm1f(v2);
  float v3 = acc.w * inv + bv.w; v3 = v3 > 0.f ? v3 : expm1f(v3);
  float p0 = v0 * w2e.x + v1 * w2e.z + v2 * w2o.x + v3 * w2o.z;
  float p1 = v0 * w2e.y + v1 * w2e.w + v2 * w2o.y + v3 * w2o.w;
#pragma unroll
  for (int off = 32; off; off >>= 1) {
    p0 += __shfl_xor(p0, off, 64);
    p1 += __shfl_xor(p1, off, 64);
  }
  if (l == 0) {
    float e2 = p0 * al2[0] + p1 * al2[1];
    float r2 = p0 * ar2[0] + p1 * ar2[1];
    node4[dn] = make_float4(p0, p1, e2, r2);
  }
}

// Wave per dst node; single float4 gather per edge; fused log_softmax.
__global__ __launch_bounds__(256) void k_agg2(
    const float4* __restrict__ node4, const int* __restrict__ offs,
    const int* __restrict__ csr, const float* __restrict__ b2,
    float* __restrict__ out, int n) {
  int dn = blockIdx.x * 4 + (threadIdx.x >> 6);
  int l = threadIdx.x & 63;
  if (dn >= n) return;
  float erd = node4[dn].w;
  int beg = offs[dn], end = offs[dn + 1];
  float den = 0.f, a0 = 0.f, a1 = 0.f;
  for (int e = beg + l; e < end; e += 64) {
    int s = csr[e];
    float4 n4 = node4[s];
    float ev = n4.z + erd;
    ev = ev >= 0.f ? ev : 0.2f * ev;
    float ee = __expf(ev);
    den += ee;
    a0 = fmaf(ee, n4.x, a0);
    a1 = fmaf(ee, n4.y, a1);
  }
#pragma unroll
  for (int off = 32; off; off >>= 1) {
    den += __shfl_xor(den, off, 64);
    a0 += __shfl_xor(a0, off, 64);
    a1 += __shfl_xor(a1, off, 64);
  }
  if (l == 0) {
    float inv = 1.f / fmaxf(den, 1e-16f);
    float z0 = a0 * inv + b2[0];
    float z1 = a1 * inv + b2[1];
    float m = fmaxf(z0, z1);
    float lse = m + logf(__expf(z0 - m) + __expf(z1 - m));
    out[dn * 2 + 0] = z0 - lse;
    out[dn * 2 + 1] = z1 - lse;
  }
}

extern "C" void kernel_launch(void* const* d_in, const int* in_sizes, int n_in,
                              void* d_out, int out_size, void* d_ws,
                              size_t ws_size, hipStream_t stream) {
  const float* x   = (const float*)d_in[0];
  const int* esrc  = (const int*)d_in[1];
  const int* edst  = (const int*)d_in[2];
  const float* W1  = (const float*)d_in[3];
  const float* al1 = (const float*)d_in[4];
  const float* ar1 = (const float*)d_in[5];
  const float* b1  = (const float*)d_in[6];
  const float* W2  = (const float*)d_in[7];
  const float* al2 = (const float*)d_in[8];
  const float* ar2 = (const float*)d_in[9];
  const float* b2  = (const float*)d_in[10];
  float* out = (float*)d_out;

  size_t off = 0;
  auto alloc = [&](size_t bytes) {
    void* p = (char*)d_ws + off;
    off += (bytes + 255) & ~(size_t)255;
    return p;
  };
  unsigned short* featb = (unsigned short*)alloc((size_t)NN * 256 * 2);
  unsigned short* W1p   = (unsigned short*)alloc((size_t)16 * 8 * 64 * 8 * 2);
  float* el1    = (float*)alloc((size_t)NN * 8 * 4);
  float* er1    = (float*)alloc((size_t)NN * 8 * 4);
  float4* node4 = (float4*)alloc((size_t)NN * 16);
  int2* stage   = (int2*)alloc((size_t)NBK * CAP * 8);
  int* csr      = (int*)alloc((size_t)NE * 4);
  int* offs     = (int*)alloc((size_t)(NN + 1) * 4);
  int* cur      = (int*)alloc((size_t)NBK * 4);
  int* bbase    = (int*)alloc((size_t)(NBK + 1) * 4);

  hipMemsetAsync(cur, 0, (size_t)NBK * 4, stream);
  k_part<<<256, 256, 0, stream>>>(edst, esrc, cur, stage, NE);
  k_bscan<<<1, 256, 0, stream>>>(cur, bbase);
  k_build<<<NBK, 256, 0, stream>>>(stage, bbase, offs, csr, NN, NE);

  k_packw<<<32, 256, 0, stream>>>(W1, W1p);
  k_gemm1m<<<(NN / 32 + 4) / 4, 256, 0, stream>>>(x, W1p, al1, ar1, featb, el1,
                                                  er1, NN);
  k_agg1<<<(NN + 3) / 4, 256, 0, stream>>>(featb, el1, er1, offs, csr, b1, W2,
                                           al2, ar2, node4, NN);
  k_agg2<<<(NN + 3) / 4, 256, 0, stream>>>(node4, offs, csr, b2, out, NN);
}

// Round 12
// 232.114 us; speedup vs baseline: 1.1529x; 1.1529x over previous
//
#include <hip/hip_runtime.h>
#include <hip/hip_fp8.h>

// GAT 2-layer. N=50000, E=1.6M (deg 32). L1: 256->8x32 (bf16 MFMA).
// feat stored FP8 e4m3 (halves agg1 gather bytes; el/er NOT from fp8).
// el/er = x @ (W1@[Ael|Aer]) via 1 extra MFMA fragment chain in gemm1m.
// CSR build: round-10 counting sort; stage packed int, csr ushort.
// agg1: wave-per-node, shuffle-shared exp, fused h@W2 -> node4.

#define NN 50000
#define NE 1600000
#define NBK 196      // coarse buckets of 256 nodes
#define PCH 6250     // edges per partition block; 256 * 6250 = NE

typedef __attribute__((ext_vector_type(8))) short short8;
typedef __attribute__((ext_vector_type(4))) float f32x4;

__device__ inline unsigned short f2bf(float f) {
  unsigned int u = __float_as_uint(f);
  unsigned int r = (u + 0x7fffu + ((u >> 16) & 1u)) >> 16;
  return (unsigned short)r;
}
__device__ inline unsigned char f2fp8(float f) {
  __hip_fp8_e4m3 q(f);
  return *reinterpret_cast<unsigned char*>(&q);
}
__device__ inline float fp82f(unsigned char b) {
  __hip_fp8_e4m3 q;
  *reinterpret_cast<unsigned char*>(&q) = b;
  return (float)q;
}
__device__ inline float lrelu_exp(float v) {
  v = v >= 0.f ? v : 0.2f * v;
  return __expf(v);
}

// coarse bucket counts via LDS hist; ~196 f&f global atomics per block.
__global__ __launch_bounds__(256) void k_bcount(const int* __restrict__ dst,
                                                int* __restrict__ bcnt, int E) {
  __shared__ int h[NBK];
  int tid = threadIdx.x;
  for (int i = tid; i < NBK; i += 256) h[i] = 0;
  __syncthreads();
  int b0 = blockIdx.x * PCH;
  for (int k = tid; k < PCH; k += 256) {
    int i = b0 + k;
    if (i < E) atomicAdd(&h[dst[i] >> 8], 1);
  }
  __syncthreads();
  for (int i = tid; i < NBK; i += 256)
    if (h[i]) atomicAdd(&bcnt[i], h[i]);
}

// scan 196 bucket counts -> bbase[0..NBK] and bcursor.
__global__ __launch_bounds__(256) void k_bscan(const int* __restrict__ bcnt,
                                               int* __restrict__ bbase,
                                               int* __restrict__ bcursor) {
  __shared__ int buf[256];
  int tid = threadIdx.x;
  int v = (tid < NBK) ? bcnt[tid] : 0;
  buf[tid] = v;
  __syncthreads();
  for (int off = 1; off < 256; off <<= 1) {
    int t = (tid >= off) ? buf[tid - off] : 0;
    __syncthreads();
    buf[tid] += t;
    __syncthreads();
  }
  int excl = buf[tid] - v;
  if (tid < NBK) { bbase[tid] = excl; bcursor[tid] = excl; }
  if (tid == NBK - 1) bbase[NBK] = buf[tid];
}

// partition into dense bucket runs; stage = ((dst&255)<<16)|src (src<65536).
__global__ __launch_bounds__(256) void k_part(const int* __restrict__ dst,
                                              const int* __restrict__ src,
                                              int* __restrict__ bcursor,
                                              int* __restrict__ stage, int E) {
  __shared__ int h[NBK], base[NBK], lofs[NBK];
  int tid = threadIdx.x;
  for (int i = tid; i < NBK; i += 256) h[i] = 0;
  __syncthreads();
  int b0 = blockIdx.x * PCH;
  for (int k = tid; k < PCH; k += 256) {
    int i = b0 + k;
    if (i < E) atomicAdd(&h[dst[i] >> 8], 1);
  }
  __syncthreads();
  for (int i = tid; i < NBK; i += 256) {
    base[i] = h[i] ? atomicAdd(&bcursor[i], h[i]) : 0;
    lofs[i] = 0;
  }
  __syncthreads();
  for (int k = tid; k < PCH; k += 256) {
    int i = b0 + k;
    if (i < E) {
      int d = dst[i];
      int b = d >> 8;
      int r = atomicAdd(&lofs[b], 1);
      stage[base[b] + r] = ((d & 255) << 16) | src[i];
    }
  }
}

// per-bucket LDS counting sort: writes offs slice + places csr (ushort).
__global__ __launch_bounds__(256) void k_build(const int* __restrict__ stage,
                                               const int* __restrict__ bbase,
                                               int* __restrict__ offs,
                                               unsigned short* __restrict__ csr,
                                               int n, int E) {
  __shared__ int h[256], buf[256], cur[256];
  int b = blockIdx.x, tid = threadIdx.x;
  int beg = bbase[b], end = bbase[b + 1];
  h[tid] = 0;
  __syncthreads();
  for (int k = beg + tid; k < end; k += 256)
    atomicAdd(&h[(stage[k] >> 16) & 255], 1);
  __syncthreads();
  int v = h[tid];
  buf[tid] = v;
  __syncthreads();
  for (int off = 1; off < 256; off <<= 1) {
    int t = (tid >= off) ? buf[tid - off] : 0;
    __syncthreads();
    buf[tid] += t;
    __syncthreads();
  }
  int excl = buf[tid] - v;
  int node = b * 256 + tid;
  if (node < n) offs[node] = beg + excl;
  if (b == 0 && tid == 0) offs[n] = E;
  cur[tid] = excl;
  __syncthreads();
  for (int k = beg + tid; k < end; k += 256) {
    int p = stage[k];
    int r = atomicAdd(&cur[(p >> 16) & 255], 1);
    csr[beg + r] = (unsigned short)(p & 0xFFFF);
  }
}

// Pack W1 into MFMA B-fragment order (bf16) + walar = W1@[Ael|Aer] fragments.
__global__ __launch_bounds__(256) void k_packw(const float* __restrict__ W1,
                                               const float* __restrict__ al,
                                               const float* __restrict__ ar,
                                               unsigned short* __restrict__ W1p,
                                               unsigned short* __restrict__ walar) {
  int idx = blockIdx.x * 256 + threadIdx.x;
  if (idx < 8192) {  // W1p
    int nf = idx >> 9, rem = idx & 511;
    int ks = rem >> 6, lane = rem & 63;
    int n = nf * 16 + (lane & 15);
    int kb = ks * 32 + (lane >> 4) * 8;
#pragma unroll
    for (int j = 0; j < 8; ++j)
      W1p[(size_t)idx * 8 + j] = f2bf(W1[(kb + j) * 256 + n]);
  } else if (idx < 8192 + 512) {  // walar: [ks][lane] frag of 256x16
    int idx2 = idx - 8192;
    int ks = idx2 >> 6, lane = idx2 & 63;
    int n = lane & 15;
    int kb = ks * 32 + (lane >> 4) * 8;
    const float* coef = (n < 8) ? (al + n * 32) : (ar + (n - 8) * 32);
    int bc = (n < 8) ? n * 32 : (n - 8) * 32;
#pragma unroll
    for (int j = 0; j < 8; ++j) {
      int k = kb + j;
      float s = 0.f;
      for (int f = 0; f < 32; ++f) s += W1[k * 256 + bc + f] * coef[f];
      walar[(size_t)idx2 * 8 + j] = f2bf(s);
    }
  }
}

// MFMA GEMM: feat_fp8 = fp8(bf16(x) @ bf16(W1)); el/er via walar MFMA chain.
__global__ __launch_bounds__(256) void k_gemm1m(
    const float* __restrict__ x, const unsigned short* __restrict__ W1p,
    const unsigned short* __restrict__ walar,
    unsigned char* __restrict__ feat8, float* __restrict__ el,
    float* __restrict__ er, int n) {
  int w = threadIdx.x >> 6, lane = threadIdx.x & 63;
  int tile = (blockIdx.x * 4 + w) * 32;
  if (tile >= n) return;
  int r0 = lane & 15, kgrp = lane >> 4;
  f32x4 acc[16][2];
  f32x4 accE[2];
#pragma unroll
  for (int nf = 0; nf < 16; ++nf)
#pragma unroll
    for (int mf = 0; mf < 2; ++mf) acc[nf][mf] = (f32x4){0.f, 0.f, 0.f, 0.f};
  accE[0] = (f32x4){0.f, 0.f, 0.f, 0.f};
  accE[1] = (f32x4){0.f, 0.f, 0.f, 0.f};

  for (int ks = 0; ks < 8; ++ks) {
    int kb = ks * 32 + kgrp * 8;
    short8 a0, a1;
    {
      int row = tile + r0;
      const float* p = x + (size_t)row * 256 + kb;
      float4 v0 = *reinterpret_cast<const float4*>(p);
      float4 v1 = *reinterpret_cast<const float4*>(p + 4);
      a0[0] = (short)f2bf(v0.x); a0[1] = (short)f2bf(v0.y);
      a0[2] = (short)f2bf(v0.z); a0[3] = (short)f2bf(v0.w);
      a0[4] = (short)f2bf(v1.x); a0[5] = (short)f2bf(v1.y);
      a0[6] = (short)f2bf(v1.z); a0[7] = (short)f2bf(v1.w);
    }
    {
      int row = tile + 16 + r0;
      if (row < n) {
        const float* p = x + (size_t)row * 256 + kb;
        float4 v0 = *reinterpret_cast<const float4*>(p);
        float4 v1 = *reinterpret_cast<const float4*>(p + 4);
        a1[0] = (short)f2bf(v0.x); a1[1] = (short)f2bf(v0.y);
        a1[2] = (short)f2bf(v0.z); a1[3] = (short)f2bf(v0.w);
        a1[4] = (short)f2bf(v1.x); a1[5] = (short)f2bf(v1.y);
        a1[6] = (short)f2bf(v1.z); a1[7] = (short)f2bf(v1.w);
      } else {
#pragma unroll
        for (int j = 0; j < 8; ++j) a1[j] = 0;
      }
    }
#pragma unroll
    for (int nf = 0; nf < 16; ++nf) {
      short8 b = *reinterpret_cast<const short8*>(
          W1p + ((size_t)(nf * 8 + ks) * 64 + lane) * 8);
      acc[nf][0] = __builtin_amdgcn_mfma_f32_16x16x32_bf16(a0, b, acc[nf][0], 0, 0, 0);
      acc[nf][1] = __builtin_amdgcn_mfma_f32_16x16x32_bf16(a1, b, acc[nf][1], 0, 0, 0);
    }
    {
      short8 bE = *reinterpret_cast<const short8*>(
          walar + ((size_t)ks * 64 + lane) * 8);
      accE[0] = __builtin_amdgcn_mfma_f32_16x16x32_bf16(a0, bE, accE[0], 0, 0, 0);
      accE[1] = __builtin_amdgcn_mfma_f32_16x16x32_bf16(a1, bE, accE[1], 0, 0, 0);
    }
  }
  // store feat fp8
#pragma unroll
  for (int nf = 0; nf < 16; ++nf)
#pragma unroll
    for (int mf = 0; mf < 2; ++mf)
#pragma unroll
      for (int q = 0; q < 4; ++q) {
        int row = tile + mf * 16 + kgrp * 4 + q;
        if (row < n)
          feat8[(size_t)row * 256 + nf * 16 + r0] = f2fp8(acc[nf][mf][q]);
      }
  // store el/er: D col c=r0 (c<8 -> el head c, else er head c-8)
#pragma unroll
  for (int mf = 0; mf < 2; ++mf)
#pragma unroll
    for (int q = 0; q < 4; ++q) {
      int row = tile + mf * 16 + kgrp * 4 + q;
      if (row < n) {
        if (r0 < 8) el[(size_t)row * 8 + r0] = accE[mf][q];
        else        er[(size_t)row * 8 + (r0 - 8)] = accE[mf][q];
      }
    }
}

// Wave per dst node. Lane l owns cols l*4..l*4+3 (head hh=l>>3).
// 8-edge groups: lane (e=l>>3, h=l&7) computes ee once; shuffle-broadcast.
__global__ __launch_bounds__(256) void k_agg1(
    const unsigned char* __restrict__ feat8, const float* __restrict__ el,
    const float* __restrict__ er, const int* __restrict__ offs,
    const unsigned short* __restrict__ csr, const float* __restrict__ b1,
    const float* __restrict__ W2, const float* __restrict__ al2,
    const float* __restrict__ ar2, float4* __restrict__ node4, int n) {
  int dn = blockIdx.x * 4 + (threadIdx.x >> 6);
  if (dn >= n) return;
  int l = threadIdx.x & 63;
  int hh = l >> 3;
  int h8 = l & 7;
  float erv = er[dn * 8 + h8];
  int beg = offs[dn], end = offs[dn + 1];
  float4 acc = {0.f, 0.f, 0.f, 0.f};
  float den = 0.f;
  int g = beg;
  for (; g + 8 <= end; g += 8) {
    int s_my = csr[g + (l >> 3)];
    float eev = lrelu_exp(el[s_my * 8 + h8] + erv);
#pragma unroll
    for (int e = 0; e < 8; ++e) {
      int s = __shfl(s_my, e * 8, 64);
      float ee = __shfl(eev, e * 8 + hh, 64);
      den += ee;
      uchar4 fv = *reinterpret_cast<const uchar4*>(feat8 + (size_t)s * 256 + l * 4);
      acc.x = fmaf(ee, fp82f(fv.x), acc.x);
      acc.y = fmaf(ee, fp82f(fv.y), acc.y);
      acc.z = fmaf(ee, fp82f(fv.z), acc.z);
      acc.w = fmaf(ee, fp82f(fv.w), acc.w);
    }
  }
  if (g < end) {
    int rem = end - g;
    int idx = g + (l >> 3);
    int s_my = csr[idx < end ? idx : end - 1];
    float eev = lrelu_exp(el[s_my * 8 + h8] + erv);
    for (int e = 0; e < rem; ++e) {
      int s = __shfl(s_my, e * 8, 64);
      float ee = __shfl(eev, e * 8 + hh, 64);
      den += ee;
      uchar4 fv = *reinterpret_cast<const uchar4*>(feat8 + (size_t)s * 256 + l * 4);
      acc.x = fmaf(ee, fp82f(fv.x), acc.x);
      acc.y = fmaf(ee, fp82f(fv.y), acc.y);
      acc.z = fmaf(ee, fp82f(fv.z), acc.z);
      acc.w = fmaf(ee, fp82f(fv.w), acc.w);
    }
  }
  float4 bv = *reinterpret_cast<const float4*>(b1 + l * 4);
  float4 w2e = *reinterpret_cast<const float4*>(W2 + l * 8);
  float4 w2o = *reinterpret_cast<const float4*>(W2 + l * 8 + 4);
  float inv = 1.f / fmaxf(den, 1e-16f);
  float v0 = acc.x * inv + bv.x; v0 = v0 > 0.f ? v0 : expm1f(v0);
  float v1 = acc.y * inv + bv.y; v1 = v1 > 0.f ? v1 : expm1f(v1);
  float v2 = acc.z * inv + bv.z; v2 = v2 > 0.f ? v2 : expm1f(v2);
  float v3 = acc.w * inv + bv.w; v3 = v3 > 0.f ? v3 : expm1f(v3);
  float p0 = v0 * w2e.x + v1 * w2e.z + v2 * w2o.x + v3 * w2o.z;
  float p1 = v0 * w2e.y + v1 * w2e.w + v2 * w2o.y + v3 * w2o.w;
#pragma unroll
  for (int off = 32; off; off >>= 1) {
    p0 += __shfl_xor(p0, off, 64);
    p1 += __shfl_xor(p1, off, 64);
  }
  if (l == 0) {
    float e2 = p0 * al2[0] + p1 * al2[1];
    float r2 = p0 * ar2[0] + p1 * ar2[1];
    node4[dn] = make_float4(p0, p1, e2, r2);
  }
}

// Wave per dst node; single float4 gather per edge; fused log_softmax.
__global__ __launch_bounds__(256) void k_agg2(
    const float4* __restrict__ node4, const int* __restrict__ offs,
    const unsigned short* __restrict__ csr, const float* __restrict__ b2,
    float* __restrict__ out, int n) {
  int dn = blockIdx.x * 4 + (threadIdx.x >> 6);
  int l = threadIdx.x & 63;
  if (dn >= n) return;
  float erd = node4[dn].w;
  int beg = offs[dn], end = offs[dn + 1];
  float den = 0.f, a0 = 0.f, a1 = 0.f;
  for (int e = beg + l; e < end; e += 64) {
    int s = csr[e];
    float4 n4 = node4[s];
    float ev = n4.z + erd;
    ev = ev >= 0.f ? ev : 0.2f * ev;
    float ee = __expf(ev);
    den += ee;
    a0 = fmaf(ee, n4.x, a0);
    a1 = fmaf(ee, n4.y, a1);
  }
#pragma unroll
  for (int off = 32; off; off >>= 1) {
    den += __shfl_xor(den, off, 64);
    a0 += __shfl_xor(a0, off, 64);
    a1 += __shfl_xor(a1, off, 64);
  }
  if (l == 0) {
    float inv = 1.f / fmaxf(den, 1e-16f);
    float z0 = a0 * inv + b2[0];
    float z1 = a1 * inv + b2[1];
    float m = fmaxf(z0, z1);
    float lse = m + logf(__expf(z0 - m) + __expf(z1 - m));
    out[dn * 2 + 0] = z0 - lse;
    out[dn * 2 + 1] = z1 - lse;
  }
}

extern "C" void kernel_launch(void* const* d_in, const int* in_sizes, int n_in,
                              void* d_out, int out_size, void* d_ws,
                              size_t ws_size, hipStream_t stream) {
  const float* x   = (const float*)d_in[0];
  const int* esrc  = (const int*)d_in[1];
  const int* edst  = (const int*)d_in[2];
  const float* W1  = (const float*)d_in[3];
  const float* al1 = (const float*)d_in[4];
  const float* ar1 = (const float*)d_in[5];
  const float* b1  = (const float*)d_in[6];
  const float* W2  = (const float*)d_in[7];
  const float* al2 = (const float*)d_in[8];
  const float* ar2 = (const float*)d_in[9];
  const float* b2  = (const float*)d_in[10];
  float* out = (float*)d_out;

  size_t off = 0;
  auto alloc = [&](size_t bytes) {
    void* p = (char*)d_ws + off;
    off += (bytes + 255) & ~(size_t)255;
    return p;
  };
  unsigned char* feat8 = (unsigned char*)alloc((size_t)NN * 256);
  unsigned short* W1p  = (unsigned short*)alloc((size_t)16 * 8 * 64 * 8 * 2);
  unsigned short* walar = (unsigned short*)alloc((size_t)8 * 64 * 8 * 2);
  float* el1    = (float*)alloc((size_t)NN * 8 * 4);
  float* er1    = (float*)alloc((size_t)NN * 8 * 4);
  float4* node4 = (float4*)alloc((size_t)NN * 16);
  int* stage    = (int*)alloc((size_t)NE * 4);
  unsigned short* csr = (unsigned short*)alloc((size_t)NE * 2);
  int* offs     = (int*)alloc((size_t)(NN + 1) * 4);
  int* bcnt     = (int*)alloc((size_t)NBK * 4);
  int* bbase    = (int*)alloc((size_t)(NBK + 1) * 4);
  int* bcursor  = (int*)alloc((size_t)NBK * 4);

  hipMemsetAsync(bcnt, 0, (size_t)NBK * 4, stream);
  k_bcount<<<256, 256, 0, stream>>>(edst, bcnt, NE);
  k_bscan<<<1, 256, 0, stream>>>(bcnt, bbase, bcursor);
  k_part<<<256, 256, 0, stream>>>(edst, esrc, bcursor, stage, NE);
  k_build<<<NBK, 256, 0, stream>>>(stage, bbase, offs, csr, NN, NE);

  k_packw<<<34, 256, 0, stream>>>(W1, al1, ar1, W1p, walar);
  k_gemm1m<<<(NN / 32 + 4) / 4, 256, 0, stream>>>(x, W1p, walar, feat8, el1,
                                                  er1, NN);
  k_agg1<<<(NN + 3) / 4, 256, 0, stream>>>(feat8, el1, er1, offs, csr, b1, W2,
                                           al2, ar2, node4, NN);
  k_agg2<<<(NN + 3) / 4, 256, 0, stream>>>(node4, offs, csr, b2, out, NN);
}

// Round 13
// 215.278 us; speedup vs baseline: 1.2431x; 1.0782x over previous
//
#include <hip/hip_runtime.h>
#include <hip/hip_fp8.h>

// GAT 2-layer. N=50000, E=1.6M (deg 32). L1: 256->8x32 (bf16 MFMA).
// feat stored FP8 e4m3; agg1 unpacks via HW cvt_pk_f32_fp8 (2B/inst).
// el/er = x @ (W1@[Ael|Aer]) via extra MFMA fragment chain in gemm1m.
// CSR build: cap-strided counting sort (part merges hist, bscan, build).
// agg1: wave-per-node, shuffle-shared exp, fused h@W2 -> node4.

#define NN 50000
#define NE 1600000
#define NBK 196      // coarse buckets of 256 nodes
#define PCH 6250     // edges per partition block; 256 * 6250 = NE
#define CAP 16384    // stage ints per bucket (mean 8192, ~90 sigma margin)

typedef __attribute__((ext_vector_type(8))) short short8;
typedef __attribute__((ext_vector_type(4))) float f32x4;
typedef __attribute__((ext_vector_type(2))) float f32x2;

__device__ inline unsigned short f2bf(float f) {
  unsigned int u = __float_as_uint(f);
  unsigned int r = (u + 0x7fffu + ((u >> 16) & 1u)) >> 16;
  return (unsigned short)r;
}
__device__ inline unsigned char f2fp8(float f) {
  __hip_fp8_e4m3 q(f);
  return *reinterpret_cast<unsigned char*>(&q);
}
__device__ inline float lrelu_exp(float v) {
  v = v >= 0.f ? v : 0.2f * v;
  return __expf(v);
}

// partition into cap-strided bucket runs (hist fused; no separate count pass).
// stage entry = ((dst&255)<<16)|src (src < 65536). cur doubles as totals.
__global__ __launch_bounds__(256) void k_part(const int* __restrict__ dst,
                                              const int* __restrict__ src,
                                              int* __restrict__ cur,
                                              int* __restrict__ stage, int E) {
  __shared__ int h[NBK], base[NBK], lofs[NBK];
  int tid = threadIdx.x;
  for (int i = tid; i < NBK; i += 256) h[i] = 0;
  __syncthreads();
  int b0 = blockIdx.x * PCH;
  for (int k = tid; k < PCH; k += 256) {
    int i = b0 + k;
    if (i < E) atomicAdd(&h[dst[i] >> 8], 1);
  }
  __syncthreads();
  for (int i = tid; i < NBK; i += 256) {
    base[i] = h[i] ? atomicAdd(&cur[i], h[i]) : 0;
    lofs[i] = 0;
  }
  __syncthreads();
  for (int k = tid; k < PCH; k += 256) {
    int i = b0 + k;
    if (i < E) {
      int d = dst[i];
      int b = d >> 8;
      int r = atomicAdd(&lofs[b], 1);
      stage[(size_t)b * CAP + base[b] + r] = ((d & 255) << 16) | src[i];
    }
  }
}

// scan bucket totals (=cur) -> bbase[0..NBK].
__global__ __launch_bounds__(256) void k_bscan(const int* __restrict__ cur,
                                               int* __restrict__ bbase) {
  __shared__ int buf[256];
  int tid = threadIdx.x;
  int v = (tid < NBK) ? cur[tid] : 0;
  buf[tid] = v;
  __syncthreads();
  for (int off = 1; off < 256; off <<= 1) {
    int t = (tid >= off) ? buf[tid - off] : 0;
    __syncthreads();
    buf[tid] += t;
    __syncthreads();
  }
  if (tid < NBK) bbase[tid] = buf[tid] - v;
  if (tid == NBK - 1) bbase[NBK] = buf[tid];
}

// per-bucket LDS counting sort: writes offs slice + places csr (ushort).
__global__ __launch_bounds__(256) void k_build(const int* __restrict__ stage,
                                               const int* __restrict__ bbase,
                                               int* __restrict__ offs,
                                               unsigned short* __restrict__ csr,
                                               int n, int E) {
  __shared__ int h[256], buf[256], cur[256];
  int b = blockIdx.x, tid = threadIdx.x;
  int beg = bbase[b];
  int tot = bbase[b + 1] - beg;
  const int* st = stage + (size_t)b * CAP;
  h[tid] = 0;
  __syncthreads();
  for (int k = tid; k < tot; k += 256)
    atomicAdd(&h[(st[k] >> 16) & 255], 1);
  __syncthreads();
  int v = h[tid];
  buf[tid] = v;
  __syncthreads();
  for (int off = 1; off < 256; off <<= 1) {
    int t = (tid >= off) ? buf[tid - off] : 0;
    __syncthreads();
    buf[tid] += t;
    __syncthreads();
  }
  int excl = buf[tid] - v;
  int node = b * 256 + tid;
  if (node < n) offs[node] = beg + excl;
  if (b == 0 && tid == 0) offs[n] = E;
  cur[tid] = excl;
  __syncthreads();
  for (int k = tid; k < tot; k += 256) {
    int p = st[k];
    int r = atomicAdd(&cur[(p >> 16) & 255], 1);
    csr[beg + r] = (unsigned short)(p & 0xFFFF);
  }
}

// Pack W1 into MFMA B-fragment order (bf16) + walar = W1@[Ael|Aer] fragments.
__global__ __launch_bounds__(256) void k_packw(const float* __restrict__ W1,
                                               const float* __restrict__ al,
                                               const float* __restrict__ ar,
                                               unsigned short* __restrict__ W1p,
                                               unsigned short* __restrict__ walar) {
  int idx = blockIdx.x * 256 + threadIdx.x;
  if (idx < 8192) {  // W1p
    int nf = idx >> 9, rem = idx & 511;
    int ks = rem >> 6, lane = rem & 63;
    int n = nf * 16 + (lane & 15);
    int kb = ks * 32 + (lane >> 4) * 8;
#pragma unroll
    for (int j = 0; j < 8; ++j)
      W1p[(size_t)idx * 8 + j] = f2bf(W1[(kb + j) * 256 + n]);
  } else if (idx < 8192 + 512) {  // walar: [ks][lane] frag of 256x16
    int idx2 = idx - 8192;
    int ks = idx2 >> 6, lane = idx2 & 63;
    int n = lane & 15;
    int kb = ks * 32 + (lane >> 4) * 8;
    const float* coef = (n < 8) ? (al + n * 32) : (ar + (n - 8) * 32);
    int bc = (n < 8) ? n * 32 : (n - 8) * 32;
#pragma unroll
    for (int j = 0; j < 8; ++j) {
      int k = kb + j;
      float s = 0.f;
      for (int f = 0; f < 32; ++f) s += W1[k * 256 + bc + f] * coef[f];
      walar[(size_t)idx2 * 8 + j] = f2bf(s);
    }
  }
}

// MFMA GEMM: feat_fp8 = fp8(bf16(x) @ bf16(W1)); el/er via walar MFMA chain.
__global__ __launch_bounds__(256) void k_gemm1m(
    const float* __restrict__ x, const unsigned short* __restrict__ W1p,
    const unsigned short* __restrict__ walar,
    unsigned char* __restrict__ feat8, float* __restrict__ el,
    float* __restrict__ er, int n) {
  int w = threadIdx.x >> 6, lane = threadIdx.x & 63;
  int tile = (blockIdx.x * 4 + w) * 32;
  if (tile >= n) return;
  int r0 = lane & 15, kgrp = lane >> 4;
  f32x4 acc[16][2];
  f32x4 accE[2];
#pragma unroll
  for (int nf = 0; nf < 16; ++nf)
#pragma unroll
    for (int mf = 0; mf < 2; ++mf) acc[nf][mf] = (f32x4){0.f, 0.f, 0.f, 0.f};
  accE[0] = (f32x4){0.f, 0.f, 0.f, 0.f};
  accE[1] = (f32x4){0.f, 0.f, 0.f, 0.f};

  for (int ks = 0; ks < 8; ++ks) {
    int kb = ks * 32 + kgrp * 8;
    short8 a0, a1;
    {
      int row = tile + r0;
      const float* p = x + (size_t)row * 256 + kb;
      float4 v0 = *reinterpret_cast<const float4*>(p);
      float4 v1 = *reinterpret_cast<const float4*>(p + 4);
      a0[0] = (short)f2bf(v0.x); a0[1] = (short)f2bf(v0.y);
      a0[2] = (short)f2bf(v0.z); a0[3] = (short)f2bf(v0.w);
      a0[4] = (short)f2bf(v1.x); a0[5] = (short)f2bf(v1.y);
      a0[6] = (short)f2bf(v1.z); a0[7] = (short)f2bf(v1.w);
    }
    {
      int row = tile + 16 + r0;
      if (row < n) {
        const float* p = x + (size_t)row * 256 + kb;
        float4 v0 = *reinterpret_cast<const float4*>(p);
        float4 v1 = *reinterpret_cast<const float4*>(p + 4);
        a1[0] = (short)f2bf(v0.x); a1[1] = (short)f2bf(v0.y);
        a1[2] = (short)f2bf(v0.z); a1[3] = (short)f2bf(v0.w);
        a1[4] = (short)f2bf(v1.x); a1[5] = (short)f2bf(v1.y);
        a1[6] = (short)f2bf(v1.z); a1[7] = (short)f2bf(v1.w);
      } else {
#pragma unroll
        for (int j = 0; j < 8; ++j) a1[j] = 0;
      }
    }
#pragma unroll
    for (int nf = 0; nf < 16; ++nf) {
      short8 b = *reinterpret_cast<const short8*>(
          W1p + ((size_t)(nf * 8 + ks) * 64 + lane) * 8);
      acc[nf][0] = __builtin_amdgcn_mfma_f32_16x16x32_bf16(a0, b, acc[nf][0], 0, 0, 0);
      acc[nf][1] = __builtin_amdgcn_mfma_f32_16x16x32_bf16(a1, b, acc[nf][1], 0, 0, 0);
    }
    {
      short8 bE = *reinterpret_cast<const short8*>(
          walar + ((size_t)ks * 64 + lane) * 8);
      accE[0] = __builtin_amdgcn_mfma_f32_16x16x32_bf16(a0, bE, accE[0], 0, 0, 0);
      accE[1] = __builtin_amdgcn_mfma_f32_16x16x32_bf16(a1, bE, accE[1], 0, 0, 0);
    }
  }
  // store feat fp8
#pragma unroll
  for (int nf = 0; nf < 16; ++nf)
#pragma unroll
    for (int mf = 0; mf < 2; ++mf)
#pragma unroll
      for (int q = 0; q < 4; ++q) {
        int row = tile + mf * 16 + kgrp * 4 + q;
        if (row < n)
          feat8[(size_t)row * 256 + nf * 16 + r0] = f2fp8(acc[nf][mf][q]);
      }
  // store el/er: D col c=r0 (c<8 -> el head c, else er head c-8)
#pragma unroll
  for (int mf = 0; mf < 2; ++mf)
#pragma unroll
    for (int q = 0; q < 4; ++q) {
      int row = tile + mf * 16 + kgrp * 4 + q;
      if (row < n) {
        if (r0 < 8) el[(size_t)row * 8 + r0] = accE[mf][q];
        else        er[(size_t)row * 8 + (r0 - 8)] = accE[mf][q];
      }
    }
}

// Wave per dst node. Lane l owns cols l*4..l*4+3 (head hh=l>>3).
// 8-edge groups: lane (e=l>>3, h=l&7) computes ee once; shuffle-broadcast.
// fp8 unpack via HW cvt_pk_f32_fp8 (bytes 0,1 / 2,3 of a dword).
__global__ __launch_bounds__(256) void k_agg1(
    const unsigned char* __restrict__ feat8, const float* __restrict__ el,
    const float* __restrict__ er, const int* __restrict__ offs,
    const unsigned short* __restrict__ csr, const float* __restrict__ b1,
    const float* __restrict__ W2, const float* __restrict__ al2,
    const float* __restrict__ ar2, float4* __restrict__ node4, int n) {
  int dn = blockIdx.x * 4 + (threadIdx.x >> 6);
  if (dn >= n) return;
  int l = threadIdx.x & 63;
  int hh = l >> 3;
  int h8 = l & 7;
  float erv = er[dn * 8 + h8];
  int beg = offs[dn], end = offs[dn + 1];
  float4 acc = {0.f, 0.f, 0.f, 0.f};
  float den = 0.f;
  int g = beg;
  for (; g + 8 <= end; g += 8) {
    int s_my = csr[g + (l >> 3)];
    float eev = lrelu_exp(el[s_my * 8 + h8] + erv);
#pragma unroll
    for (int e = 0; e < 8; ++e) {
      int s = __shfl(s_my, e * 8, 64);
      float ee = __shfl(eev, e * 8 + hh, 64);
      den += ee;
      unsigned int fv = *reinterpret_cast<const unsigned int*>(
          feat8 + (size_t)s * 256 + l * 4);
      f32x2 lo = __builtin_amdgcn_cvt_pk_f32_fp8(fv, false);
      f32x2 hi = __builtin_amdgcn_cvt_pk_f32_fp8(fv, true);
      acc.x = fmaf(ee, lo[0], acc.x);
      acc.y = fmaf(ee, lo[1], acc.y);
      acc.z = fmaf(ee, hi[0], acc.z);
      acc.w = fmaf(ee, hi[1], acc.w);
    }
  }
  if (g < end) {
    int rem = end - g;
    int idx = g + (l >> 3);
    int s_my = csr[idx < end ? idx : end - 1];
    float eev = lrelu_exp(el[s_my * 8 + h8] + erv);
    for (int e = 0; e < rem; ++e) {
      int s = __shfl(s_my, e * 8, 64);
      float ee = __shfl(eev, e * 8 + hh, 64);
      den += ee;
      unsigned int fv = *reinterpret_cast<const unsigned int*>(
          feat8 + (size_t)s * 256 + l * 4);
      f32x2 lo = __builtin_amdgcn_cvt_pk_f32_fp8(fv, false);
      f32x2 hi = __builtin_amdgcn_cvt_pk_f32_fp8(fv, true);
      acc.x = fmaf(ee, lo[0], acc.x);
      acc.y = fmaf(ee, lo[1], acc.y);
      acc.z = fmaf(ee, hi[0], acc.z);
      acc.w = fmaf(ee, hi[1], acc.w);
    }
  }
  float4 bv = *reinterpret_cast<const float4*>(b1 + l * 4);
  float4 w2e = *reinterpret_cast<const float4*>(W2 + l * 8);
  float4 w2o = *reinterpret_cast<const float4*>(W2 + l * 8 + 4);
  float inv = 1.f / fmaxf(den, 1e-16f);
  float v0 = acc.x * inv + bv.x; v0 = v0 > 0.f ? v0 : expm1f(v0);
  float v1 = acc.y * inv + bv.y; v1 = v1 > 0.f ? v1 : expm1f(v1);
  float v2 = acc.z * inv + bv.z; v2 = v2 > 0.f ? v2 : expm1f(v2);
  float v3 = acc.w * inv + bv.w; v3 = v3 > 0.f ? v3 : expm1f(v3);
  float p0 = v0 * w2e.x + v1 * w2e.z + v2 * w2o.x + v3 * w2o.z;
  float p1 = v0 * w2e.y + v1 * w2e.w + v2 * w2o.y + v3 * w2o.w;
#pragma unroll
  for (int off = 32; off; off >>= 1) {
    p0 += __shfl_xor(p0, off, 64);
    p1 += __shfl_xor(p1, off, 64);
  }
  if (l == 0) {
    float e2 = p0 * al2[0] + p1 * al2[1];
    float r2 = p0 * ar2[0] + p1 * ar2[1];
    node4[dn] = make_float4(p0, p1, e2, r2);
  }
}

// Wave per dst node; single float4 gather per edge; fused log_softmax.
__global__ __launch_bounds__(256) void k_agg2(
    const float4* __restrict__ node4, const int* __restrict__ offs,
    const unsigned short* __restrict__ csr, const float* __restrict__ b2,
    float* __restrict__ out, int n) {
  int dn = blockIdx.x * 4 + (threadIdx.x >> 6);
  int l = threadIdx.x & 63;
  if (dn >= n) return;
  float erd = node4[dn].w;
  int beg = offs[dn], end = offs[dn + 1];
  float den = 0.f, a0 = 0.f, a1 = 0.f;
  for (int e = beg + l; e < end; e += 64) {
    int s = csr[e];
    float4 n4 = node4[s];
    float ev = n4.z + erd;
    ev = ev >= 0.f ? ev : 0.2f * ev;
    float ee = __expf(ev);
    den += ee;
    a0 = fmaf(ee, n4.x, a0);
    a1 = fmaf(ee, n4.y, a1);
  }
#pragma unroll
  for (int off = 32; off; off >>= 1) {
    den += __shfl_xor(den, off, 64);
    a0 += __shfl_xor(a0, off, 64);
    a1 += __shfl_xor(a1, off, 64);
  }
  if (l == 0) {
    float inv = 1.f / fmaxf(den, 1e-16f);
    float z0 = a0 * inv + b2[0];
    float z1 = a1 * inv + b2[1];
    float m = fmaxf(z0, z1);
    float lse = m + logf(__expf(z0 - m) + __expf(z1 - m));
    out[dn * 2 + 0] = z0 - lse;
    out[dn * 2 + 1] = z1 - lse;
  }
}

extern "C" void kernel_launch(void* const* d_in, const int* in_sizes, int n_in,
                              void* d_out, int out_size, void* d_ws,
                              size_t ws_size, hipStream_t stream) {
  const float* x   = (const float*)d_in[0];
  const int* esrc  = (const int*)d_in[1];
  const int* edst  = (const int*)d_in[2];
  const float* W1  = (const float*)d_in[3];
  const float* al1 = (const float*)d_in[4];
  const float* ar1 = (const float*)d_in[5];
  const float* b1  = (const float*)d_in[6];
  const float* W2  = (const float*)d_in[7];
  const float* al2 = (const float*)d_in[8];
  const float* ar2 = (const float*)d_in[9];
  const float* b2  = (const float*)d_in[10];
  float* out = (float*)d_out;

  size_t off = 0;
  auto alloc = [&](size_t bytes) {
    void* p = (char*)d_ws + off;
    off += (bytes + 255) & ~(size_t)255;
    return p;
  };
  unsigned char* feat8 = (unsigned char*)alloc((size_t)NN * 256);
  unsigned short* W1p  = (unsigned short*)alloc((size_t)16 * 8 * 64 * 8 * 2);
  unsigned short* walar = (unsigned short*)alloc((size_t)8 * 64 * 8 * 2);
  float* el1    = (float*)alloc((size_t)NN * 8 * 4);
  float* er1    = (float*)alloc((size_t)NN * 8 * 4);
  float4* node4 = (float4*)alloc((size_t)NN * 16);
  int* stage    = (int*)alloc((size_t)NBK * CAP * 4);
  unsigned short* csr = (unsigned short*)alloc((size_t)NE * 2);
  int* offs     = (int*)alloc((size_t)(NN + 1) * 4);
  int* cur      = (int*)alloc((size_t)NBK * 4);
  int* bbase    = (int*)alloc((size_t)(NBK + 1) * 4);

  hipMemsetAsync(cur, 0, (size_t)NBK * 4, stream);
  k_part<<<256, 256, 0, stream>>>(edst, esrc, cur, stage, NE);
  k_bscan<<<1, 256, 0, stream>>>(cur, bbase);
  k_build<<<NBK, 256, 0, stream>>>(stage, bbase, offs, csr, NN, NE);

  k_packw<<<34, 256, 0, stream>>>(W1, al1, ar1, W1p, walar);
  k_gemm1m<<<(NN / 32 + 4) / 4, 256, 0, stream>>>(x, W1p, walar, feat8, el1,
                                                  er1, NN);
  k_agg1<<<(NN + 3) / 4, 256, 0, stream>>>(feat8, el1, er1, offs, csr, b1, W2,
                                           al2, ar2, node4, NN);
  k_agg2<<<(NN + 3) / 4, 256, 0, stream>>>(node4, offs, csr, b2, out, NN);
}

// Round 14
// 213.386 us; speedup vs baseline: 1.2541x; 1.0089x over previous
//
#include <hip/hip_runtime.h>
#include <hip/hip_fp8.h>

// GAT 2-layer. N=50000, E=1.6M (deg 32). L1: 256->8x32 (bf16 MFMA).
// feat stored FP8 e4m3; agg1 unpacks via HW cvt_pk_f32_fp8, packed-fma
// accumulate, readlane (SGPR row base) for src broadcast.
// el/er = x @ (W1@[Ael|Aer]) via extra MFMA fragment chain in gemm1m.
// CSR build: LDS-sorted partition (coalesced stage writes) -> bscan -> build.

#define NN 50000
#define NE 1600000
#define NBK 196      // coarse buckets of 256 nodes
#define PCH 6250     // edges per partition block; 256 * 6250 = NE
#define CAP 16384    // stage ints per bucket (mean 8192, ~90 sigma margin)

typedef __attribute__((ext_vector_type(8))) short short8;
typedef __attribute__((ext_vector_type(4))) float f32x4;
typedef __attribute__((ext_vector_type(2))) float f32x2;

__device__ inline unsigned short f2bf(float f) {
  unsigned int u = __float_as_uint(f);
  unsigned int r = (u + 0x7fffu + ((u >> 16) & 1u)) >> 16;
  return (unsigned short)r;
}
__device__ inline unsigned char f2fp8(float f) {
  __hip_fp8_e4m3 q(f);
  return *reinterpret_cast<unsigned char*>(&q);
}
__device__ inline float lrelu_exp(float v) {
  v = v >= 0.f ? v : 0.2f * v;
  return __expf(v);
}

// LDS bucket-sort partition: hist -> scan -> reserve -> LDS scatter ->
// coalesced copy-out. Entry = (bucket<<24)|((dst&255)<<16)|src.
__global__ __launch_bounds__(256) void k_part(const int* __restrict__ dst,
                                              const int* __restrict__ src,
                                              int* __restrict__ cur,
                                              int* __restrict__ stage, int E) {
  __shared__ int sbuf[PCH];
  __shared__ int h[NBK], scn[NBK], base[NBK], lofs[NBK];
  __shared__ int sc[256];
  int tid = threadIdx.x;
  for (int i = tid; i < NBK; i += 256) { h[i] = 0; lofs[i] = 0; }
  __syncthreads();
  int b0 = blockIdx.x * PCH;
  int tot = min(PCH, E - b0);
  for (int k = tid; k < tot; k += 256)
    atomicAdd(&h[dst[b0 + k] >> 8], 1);
  __syncthreads();
  int v = (tid < NBK) ? h[tid] : 0;
  sc[tid] = v;
  __syncthreads();
  for (int off = 1; off < 256; off <<= 1) {
    int t = (tid >= off) ? sc[tid - off] : 0;
    __syncthreads();
    sc[tid] += t;
    __syncthreads();
  }
  if (tid < NBK) {
    scn[tid] = sc[tid] - v;
    base[tid] = v ? atomicAdd(&cur[tid], v) : 0;
  }
  __syncthreads();
  for (int k = tid; k < tot; k += 256) {
    int i = b0 + k;
    int d = dst[i];
    int b = d >> 8;
    int r = atomicAdd(&lofs[b], 1);
    sbuf[scn[b] + r] = (b << 24) | ((d & 255) << 16) | src[i];
  }
  __syncthreads();
  for (int i = tid; i < tot; i += 256) {
    int e = sbuf[i];
    int b = (unsigned)e >> 24;
    stage[(size_t)b * CAP + base[b] + (i - scn[b])] = e;
  }
}

// scan bucket totals (=cur) -> bbase[0..NBK].
__global__ __launch_bounds__(256) void k_bscan(const int* __restrict__ cur,
                                               int* __restrict__ bbase) {
  __shared__ int buf[256];
  int tid = threadIdx.x;
  int v = (tid < NBK) ? cur[tid] : 0;
  buf[tid] = v;
  __syncthreads();
  for (int off = 1; off < 256; off <<= 1) {
    int t = (tid >= off) ? buf[tid - off] : 0;
    __syncthreads();
    buf[tid] += t;
    __syncthreads();
  }
  if (tid < NBK) bbase[tid] = buf[tid] - v;
  if (tid == NBK - 1) bbase[NBK] = buf[tid];
}

// per-bucket LDS counting sort: writes offs slice + places csr (ushort).
__global__ __launch_bounds__(256) void k_build(const int* __restrict__ stage,
                                               const int* __restrict__ bbase,
                                               int* __restrict__ offs,
                                               unsigned short* __restrict__ csr,
                                               int n, int E) {
  __shared__ int h[256], buf[256], cur[256];
  int b = blockIdx.x, tid = threadIdx.x;
  int beg = bbase[b];
  int tot = bbase[b + 1] - beg;
  const int* st = stage + (size_t)b * CAP;
  h[tid] = 0;
  __syncthreads();
  for (int k = tid; k < tot; k += 256)
    atomicAdd(&h[(st[k] >> 16) & 255], 1);
  __syncthreads();
  int v = h[tid];
  buf[tid] = v;
  __syncthreads();
  for (int off = 1; off < 256; off <<= 1) {
    int t = (tid >= off) ? buf[tid - off] : 0;
    __syncthreads();
    buf[tid] += t;
    __syncthreads();
  }
  int excl = buf[tid] - v;
  int node = b * 256 + tid;
  if (node < n) offs[node] = beg + excl;
  if (b == 0 && tid == 0) offs[n] = E;
  cur[tid] = excl;
  __syncthreads();
  for (int k = tid; k < tot; k += 256) {
    int p = st[k];
    int r = atomicAdd(&cur[(p >> 16) & 255], 1);
    csr[beg + r] = (unsigned short)(p & 0xFFFF);
  }
}

// Pack W1 into MFMA B-fragment order (bf16) + walar = W1@[Ael|Aer] fragments.
__global__ __launch_bounds__(256) void k_packw(const float* __restrict__ W1,
                                               const float* __restrict__ al,
                                               const float* __restrict__ ar,
                                               unsigned short* __restrict__ W1p,
                                               unsigned short* __restrict__ walar) {
  int idx = blockIdx.x * 256 + threadIdx.x;
  if (idx < 8192) {  // W1p
    int nf = idx >> 9, rem = idx & 511;
    int ks = rem >> 6, lane = rem & 63;
    int n = nf * 16 + (lane & 15);
    int kb = ks * 32 + (lane >> 4) * 8;
#pragma unroll
    for (int j = 0; j < 8; ++j)
      W1p[(size_t)idx * 8 + j] = f2bf(W1[(kb + j) * 256 + n]);
  } else if (idx < 8192 + 512) {  // walar: [ks][lane] frag of 256x16
    int idx2 = idx - 8192;
    int ks = idx2 >> 6, lane = idx2 & 63;
    int n = lane & 15;
    int kb = ks * 32 + (lane >> 4) * 8;
    const float* coef = (n < 8) ? (al + n * 32) : (ar + (n - 8) * 32);
    int bc = (n < 8) ? n * 32 : (n - 8) * 32;
#pragma unroll
    for (int j = 0; j < 8; ++j) {
      int k = kb + j;
      float s = 0.f;
      for (int f = 0; f < 32; ++f) s += W1[k * 256 + bc + f] * coef[f];
      walar[(size_t)idx2 * 8 + j] = f2bf(s);
    }
  }
}

// MFMA GEMM: feat_fp8 = fp8(bf16(x) @ bf16(W1)); el/er via walar MFMA chain.
__global__ __launch_bounds__(256) void k_gemm1m(
    const float* __restrict__ x, const unsigned short* __restrict__ W1p,
    const unsigned short* __restrict__ walar,
    unsigned char* __restrict__ feat8, float* __restrict__ el,
    float* __restrict__ er, int n) {
  int w = threadIdx.x >> 6, lane = threadIdx.x & 63;
  int tile = (blockIdx.x * 4 + w) * 32;
  if (tile >= n) return;
  int r0 = lane & 15, kgrp = lane >> 4;
  f32x4 acc[16][2];
  f32x4 accE[2];
#pragma unroll
  for (int nf = 0; nf < 16; ++nf)
#pragma unroll
    for (int mf = 0; mf < 2; ++mf) acc[nf][mf] = (f32x4){0.f, 0.f, 0.f, 0.f};
  accE[0] = (f32x4){0.f, 0.f, 0.f, 0.f};
  accE[1] = (f32x4){0.f, 0.f, 0.f, 0.f};

  for (int ks = 0; ks < 8; ++ks) {
    int kb = ks * 32 + kgrp * 8;
    short8 a0, a1;
    {
      int row = tile + r0;
      const float* p = x + (size_t)row * 256 + kb;
      float4 v0 = *reinterpret_cast<const float4*>(p);
      float4 v1 = *reinterpret_cast<const float4*>(p + 4);
      a0[0] = (short)f2bf(v0.x); a0[1] = (short)f2bf(v0.y);
      a0[2] = (short)f2bf(v0.z); a0[3] = (short)f2bf(v0.w);
      a0[4] = (short)f2bf(v1.x); a0[5] = (short)f2bf(v1.y);
      a0[6] = (short)f2bf(v1.z); a0[7] = (short)f2bf(v1.w);
    }
    {
      int row = tile + 16 + r0;
      if (row < n) {
        const float* p = x + (size_t)row * 256 + kb;
        float4 v0 = *reinterpret_cast<const float4*>(p);
        float4 v1 = *reinterpret_cast<const float4*>(p + 4);
        a1[0] = (short)f2bf(v0.x); a1[1] = (short)f2bf(v0.y);
        a1[2] = (short)f2bf(v0.z); a1[3] = (short)f2bf(v0.w);
        a1[4] = (short)f2bf(v1.x); a1[5] = (short)f2bf(v1.y);
        a1[6] = (short)f2bf(v1.z); a1[7] = (short)f2bf(v1.w);
      } else {
#pragma unroll
        for (int j = 0; j < 8; ++j) a1[j] = 0;
      }
    }
#pragma unroll
    for (int nf = 0; nf < 16; ++nf) {
      short8 b = *reinterpret_cast<const short8*>(
          W1p + ((size_t)(nf * 8 + ks) * 64 + lane) * 8);
      acc[nf][0] = __builtin_amdgcn_mfma_f32_16x16x32_bf16(a0, b, acc[nf][0], 0, 0, 0);
      acc[nf][1] = __builtin_amdgcn_mfma_f32_16x16x32_bf16(a1, b, acc[nf][1], 0, 0, 0);
    }
    {
      short8 bE = *reinterpret_cast<const short8*>(
          walar + ((size_t)ks * 64 + lane) * 8);
      accE[0] = __builtin_amdgcn_mfma_f32_16x16x32_bf16(a0, bE, accE[0], 0, 0, 0);
      accE[1] = __builtin_amdgcn_mfma_f32_16x16x32_bf16(a1, bE, accE[1], 0, 0, 0);
    }
  }
  // store feat fp8
#pragma unroll
  for (int nf = 0; nf < 16; ++nf)
#pragma unroll
    for (int mf = 0; mf < 2; ++mf)
#pragma unroll
      for (int q = 0; q < 4; ++q) {
        int row = tile + mf * 16 + kgrp * 4 + q;
        if (row < n)
          feat8[(size_t)row * 256 + nf * 16 + r0] = f2fp8(acc[nf][mf][q]);
      }
  // store el/er: D col c=r0 (c<8 -> el head c, else er head c-8)
#pragma unroll
  for (int mf = 0; mf < 2; ++mf)
#pragma unroll
    for (int q = 0; q < 4; ++q) {
      int row = tile + mf * 16 + kgrp * 4 + q;
      if (row < n) {
        if (r0 < 8) el[(size_t)row * 8 + r0] = accE[mf][q];
        else        er[(size_t)row * 8 + (r0 - 8)] = accE[mf][q];
      }
    }
}

// Wave per dst node. Lane l owns cols l*4..l*4+3 (head hh=l>>3).
// 8-edge groups: lane (e=l>>3, h=l&7) computes ee once. s via readlane
// (SGPR row base -> scalar addressing); ee via one bpermute; packed fma.
__global__ __launch_bounds__(256) void k_agg1(
    const unsigned char* __restrict__ feat8, const float* __restrict__ el,
    const float* __restrict__ er, const int* __restrict__ offs,
    const unsigned short* __restrict__ csr, const float* __restrict__ b1,
    const float* __restrict__ W2, const float* __restrict__ al2,
    const float* __restrict__ ar2, float4* __restrict__ node4, int n) {
  int dn = blockIdx.x * 4 + (threadIdx.x >> 6);
  if (dn >= n) return;
  int l = threadIdx.x & 63;
  int hh = l >> 3;
  int h8 = l & 7;
  float erv = er[dn * 8 + h8];
  int beg = offs[dn], end = offs[dn + 1];
  f32x2 acc01 = {0.f, 0.f}, acc23 = {0.f, 0.f};
  float den = 0.f;
  int g = beg;
  for (; g + 8 <= end; g += 8) {
    int s_my = csr[g + (l >> 3)];
    float eev = lrelu_exp(el[s_my * 8 + h8] + erv);
#pragma unroll
    for (int e = 0; e < 8; ++e) {
      int s = __builtin_amdgcn_readlane(s_my, e * 8);  // uniform -> SGPR
      float ee = __shfl(eev, e * 8 + hh, 64);
      den += ee;
      const unsigned char* rowp = feat8 + (size_t)s * 256;  // scalar base
      unsigned int fv = *reinterpret_cast<const unsigned int*>(rowp + l * 4);
      f32x2 lo = __builtin_amdgcn_cvt_pk_f32_fp8(fv, false);
      f32x2 hi = __builtin_amdgcn_cvt_pk_f32_fp8(fv, true);
      f32x2 ee2 = {ee, ee};
      acc01 = ee2 * lo + acc01;
      acc23 = ee2 * hi + acc23;
    }
  }
  if (g < end) {
    int rem = end - g;
    int idx = g + (l >> 3);
    int s_t = csr[idx < end ? idx : end - 1];
    float ee_t = lrelu_exp(el[s_t * 8 + h8] + erv);
    for (int e = 0; e < rem; ++e) {
      int s = __builtin_amdgcn_readlane(s_t, e * 8);
      float ee = __shfl(ee_t, e * 8 + hh, 64);
      den += ee;
      const unsigned char* rowp = feat8 + (size_t)s * 256;
      unsigned int fv = *reinterpret_cast<const unsigned int*>(rowp + l * 4);
      f32x2 lo = __builtin_amdgcn_cvt_pk_f32_fp8(fv, false);
      f32x2 hi = __builtin_amdgcn_cvt_pk_f32_fp8(fv, true);
      f32x2 ee2 = {ee, ee};
      acc01 = ee2 * lo + acc01;
      acc23 = ee2 * hi + acc23;
    }
  }
  float4 bv = *reinterpret_cast<const float4*>(b1 + l * 4);
  float4 w2e = *reinterpret_cast<const float4*>(W2 + l * 8);
  float4 w2o = *reinterpret_cast<const float4*>(W2 + l * 8 + 4);
  float inv = 1.f / fmaxf(den, 1e-16f);
  float v0 = acc01[0] * inv + bv.x; v0 = v0 > 0.f ? v0 : expm1f(v0);
  float v1 = acc01[1] * inv + bv.y; v1 = v1 > 0.f ? v1 : expm1f(v1);
  float v2 = acc23[0] * inv + bv.z; v2 = v2 > 0.f ? v2 : expm1f(v2);
  float v3 = acc23[1] * inv + bv.w; v3 = v3 > 0.f ? v3 : expm1f(v3);
  float p0 = v0 * w2e.x + v1 * w2e.z + v2 * w2o.x + v3 * w2o.z;
  float p1 = v0 * w2e.y + v1 * w2e.w + v2 * w2o.y + v3 * w2o.w;
#pragma unroll
  for (int off = 32; off; off >>= 1) {
    p0 += __shfl_xor(p0, off, 64);
    p1 += __shfl_xor(p1, off, 64);
  }
  if (l == 0) {
    float e2 = p0 * al2[0] + p1 * al2[1];
    float r2 = p0 * ar2[0] + p1 * ar2[1];
    node4[dn] = make_float4(p0, p1, e2, r2);
  }
}

// Wave per dst node; single float4 gather per edge; fused log_softmax.
__global__ __launch_bounds__(256) void k_agg2(
    const float4* __restrict__ node4, const int* __restrict__ offs,
    const unsigned short* __restrict__ csr, const float* __restrict__ b2,
    float* __restrict__ out, int n) {
  int dn = blockIdx.x * 4 + (threadIdx.x >> 6);
  int l = threadIdx.x & 63;
  if (dn >= n) return;
  float erd = node4[dn].w;
  int beg = offs[dn], end = offs[dn + 1];
  float den = 0.f, a0 = 0.f, a1 = 0.f;
  for (int e = beg + l; e < end; e += 64) {
    int s = csr[e];
    float4 n4 = node4[s];
    float ev = n4.z + erd;
    ev = ev >= 0.f ? ev : 0.2f * ev;
    float ee = __expf(ev);
    den += ee;
    a0 = fmaf(ee, n4.x, a0);
    a1 = fmaf(ee, n4.y, a1);
  }
#pragma unroll
  for (int off = 32; off; off >>= 1) {
    den += __shfl_xor(den, off, 64);
    a0 += __shfl_xor(a0, off, 64);
    a1 += __shfl_xor(a1, off, 64);
  }
  if (l == 0) {
    float inv = 1.f / fmaxf(den, 1e-16f);
    float z0 = a0 * inv + b2[0];
    float z1 = a1 * inv + b2[1];
    float m = fmaxf(z0, z1);
    float lse = m + logf(__expf(z0 - m) + __expf(z1 - m));
    out[dn * 2 + 0] = z0 - lse;
    out[dn * 2 + 1] = z1 - lse;
  }
}

extern "C" void kernel_launch(void* const* d_in, const int* in_sizes, int n_in,
                              void* d_out, int out_size, void* d_ws,
                              size_t ws_size, hipStream_t stream) {
  const float* x   = (const float*)d_in[0];
  const int* esrc  = (const int*)d_in[1];
  const int* edst  = (const int*)d_in[2];
  const float* W1  = (const float*)d_in[3];
  const float* al1 = (const float*)d_in[4];
  const float* ar1 = (const float*)d_in[5];
  const float* b1  = (const float*)d_in[6];
  const float* W2  = (const float*)d_in[7];
  const float* al2 = (const float*)d_in[8];
  const float* ar2 = (const float*)d_in[9];
  const float* b2  = (const float*)d_in[10];
  float* out = (float*)d_out;

  size_t off = 0;
  auto alloc = [&](size_t bytes) {
    void* p = (char*)d_ws + off;
    off += (bytes + 255) & ~(size_t)255;
    return p;
  };
  unsigned char* feat8 = (unsigned char*)alloc((size_t)NN * 256);
  unsigned short* W1p  = (unsigned short*)alloc((size_t)16 * 8 * 64 * 8 * 2);
  unsigned short* walar = (unsigned short*)alloc((size_t)8 * 64 * 8 * 2);
  float* el1    = (float*)alloc((size_t)NN * 8 * 4);
  float* er1    = (float*)alloc((size_t)NN * 8 * 4);
  float4* node4 = (float4*)alloc((size_t)NN * 16);
  int* stage    = (int*)alloc((size_t)NBK * CAP * 4);
  unsigned short* csr = (unsigned short*)alloc((size_t)NE * 2);
  int* offs     = (int*)alloc((size_t)(NN + 1) * 4);
  int* cur      = (int*)alloc((size_t)NBK * 4);
  int* bbase    = (int*)alloc((size_t)(NBK + 1) * 4);

  hipMemsetAsync(cur, 0, (size_t)NBK * 4, stream);
  k_part<<<256, 256, 0, stream>>>(edst, esrc, cur, stage, NE);
  k_bscan<<<1, 256, 0, stream>>>(cur, bbase);
  k_build<<<NBK, 256, 0, stream>>>(stage, bbase, offs, csr, NN, NE);

  k_packw<<<34, 256, 0, stream>>>(W1, al1, ar1, W1p, walar);
  k_gemm1m<<<(NN / 32 + 4) / 4, 256, 0, stream>>>(x, W1p, walar, feat8, el1,
                                                  er1, NN);
  k_agg1<<<(NN + 3) / 4, 256, 0, stream>>>(feat8, el1, er1, offs, csr, b1, W2,
                                           al2, ar2, node4, NN);
  k_agg2<<<(NN + 3) / 4, 256, 0, stream>>>(node4, offs, csr, b2, out, NN);
}

// Round 15
// 193.220 us; speedup vs baseline: 1.3850x; 1.1044x over previous
//
#include <hip/hip_runtime.h>
#include <hip/hip_fp8.h>

// GAT 2-layer. N=50000, E=1.6M (deg 32). L1: 256->8x32 (bf16 MFMA).
// feat stored FP8 e4m3; agg1 unpacks via HW cvt_pk_f32_fp8, packed-fma
// accumulate, readlane (SGPR row base) for src broadcast.
// gemm1m: block=32-row tile, 4 waves x 64-col groups (acc 32 VGPR/wave ->
// load pipelining + 6 waves/SIMD; was 128 acc VGPR @ 1.5 waves/SIMD).
// el/er = x @ (W1@[Ael|Aer]) via extra MFMA chain on wave 0.
// CSR build: LDS-sorted partition (coalesced stage writes) -> bscan -> build.

#define NN 50000
#define NE 1600000
#define NBK 196      // coarse buckets of 256 nodes
#define PCH 6250     // edges per partition block; 256 * 6250 = NE
#define CAP 16384    // stage ints per bucket (mean 8192, ~90 sigma margin)

typedef __attribute__((ext_vector_type(8))) short short8;
typedef __attribute__((ext_vector_type(4))) float f32x4;
typedef __attribute__((ext_vector_type(2))) float f32x2;

__device__ inline unsigned short f2bf(float f) {
  unsigned int u = __float_as_uint(f);
  unsigned int r = (u + 0x7fffu + ((u >> 16) & 1u)) >> 16;
  return (unsigned short)r;
}
__device__ inline unsigned char f2fp8(float f) {
  __hip_fp8_e4m3 q(f);
  return *reinterpret_cast<unsigned char*>(&q);
}
__device__ inline float lrelu_exp(float v) {
  v = v >= 0.f ? v : 0.2f * v;
  return __expf(v);
}

// LDS bucket-sort partition: hist -> scan -> reserve -> LDS scatter ->
// coalesced copy-out. Entry = (bucket<<24)|((dst&255)<<16)|src.
__global__ __launch_bounds__(256) void k_part(const int* __restrict__ dst,
                                              const int* __restrict__ src,
                                              int* __restrict__ cur,
                                              int* __restrict__ stage, int E) {
  __shared__ int sbuf[PCH];
  __shared__ int h[NBK], scn[NBK], base[NBK], lofs[NBK];
  __shared__ int sc[256];
  int tid = threadIdx.x;
  for (int i = tid; i < NBK; i += 256) { h[i] = 0; lofs[i] = 0; }
  __syncthreads();
  int b0 = blockIdx.x * PCH;
  int tot = min(PCH, E - b0);
  for (int k = tid; k < tot; k += 256)
    atomicAdd(&h[dst[b0 + k] >> 8], 1);
  __syncthreads();
  int v = (tid < NBK) ? h[tid] : 0;
  sc[tid] = v;
  __syncthreads();
  for (int off = 1; off < 256; off <<= 1) {
    int t = (tid >= off) ? sc[tid - off] : 0;
    __syncthreads();
    sc[tid] += t;
    __syncthreads();
  }
  if (tid < NBK) {
    scn[tid] = sc[tid] - v;
    base[tid] = v ? atomicAdd(&cur[tid], v) : 0;
  }
  __syncthreads();
  for (int k = tid; k < tot; k += 256) {
    int i = b0 + k;
    int d = dst[i];
    int b = d >> 8;
    int r = atomicAdd(&lofs[b], 1);
    sbuf[scn[b] + r] = (b << 24) | ((d & 255) << 16) | src[i];
  }
  __syncthreads();
  for (int i = tid; i < tot; i += 256) {
    int e = sbuf[i];
    int b = (unsigned)e >> 24;
    stage[(size_t)b * CAP + base[b] + (i - scn[b])] = e;
  }
}

// scan bucket totals (=cur) -> bbase[0..NBK].
__global__ __launch_bounds__(256) void k_bscan(const int* __restrict__ cur,
                                               int* __restrict__ bbase) {
  __shared__ int buf[256];
  int tid = threadIdx.x;
  int v = (tid < NBK) ? cur[tid] : 0;
  buf[tid] = v;
  __syncthreads();
  for (int off = 1; off < 256; off <<= 1) {
    int t = (tid >= off) ? buf[tid - off] : 0;
    __syncthreads();
    buf[tid] += t;
    __syncthreads();
  }
  if (tid < NBK) bbase[tid] = buf[tid] - v;
  if (tid == NBK - 1) bbase[NBK] = buf[tid];
}

// per-bucket LDS counting sort: writes offs slice + places csr (ushort).
__global__ __launch_bounds__(256) void k_build(const int* __restrict__ stage,
                                               const int* __restrict__ bbase,
                                               int* __restrict__ offs,
                                               unsigned short* __restrict__ csr,
                                               int n, int E) {
  __shared__ int h[256], buf[256], cur[256];
  int b = blockIdx.x, tid = threadIdx.x;
  int beg = bbase[b];
  int tot = bbase[b + 1] - beg;
  const int* st = stage + (size_t)b * CAP;
  h[tid] = 0;
  __syncthreads();
  for (int k = tid; k < tot; k += 256)
    atomicAdd(&h[(st[k] >> 16) & 255], 1);
  __syncthreads();
  int v = h[tid];
  buf[tid] = v;
  __syncthreads();
  for (int off = 1; off < 256; off <<= 1) {
    int t = (tid >= off) ? buf[tid - off] : 0;
    __syncthreads();
    buf[tid] += t;
    __syncthreads();
  }
  int excl = buf[tid] - v;
  int node = b * 256 + tid;
  if (node < n) offs[node] = beg + excl;
  if (b == 0 && tid == 0) offs[n] = E;
  cur[tid] = excl;
  __syncthreads();
  for (int k = tid; k < tot; k += 256) {
    int p = st[k];
    int r = atomicAdd(&cur[(p >> 16) & 255], 1);
    csr[beg + r] = (unsigned short)(p & 0xFFFF);
  }
}

// Pack W1 into MFMA B-fragment order (bf16) + walar = W1@[Ael|Aer] fragments.
__global__ __launch_bounds__(256) void k_packw(const float* __restrict__ W1,
                                               const float* __restrict__ al,
                                               const float* __restrict__ ar,
                                               unsigned short* __restrict__ W1p,
                                               unsigned short* __restrict__ walar) {
  int idx = blockIdx.x * 256 + threadIdx.x;
  if (idx < 8192) {  // W1p
    int nf = idx >> 9, rem = idx & 511;
    int ks = rem >> 6, lane = rem & 63;
    int n = nf * 16 + (lane & 15);
    int kb = ks * 32 + (lane >> 4) * 8;
#pragma unroll
    for (int j = 0; j < 8; ++j)
      W1p[(size_t)idx * 8 + j] = f2bf(W1[(kb + j) * 256 + n]);
  } else if (idx < 8192 + 512) {  // walar: [ks][lane] frag of 256x16
    int idx2 = idx - 8192;
    int ks = idx2 >> 6, lane = idx2 & 63;
    int n = lane & 15;
    int kb = ks * 32 + (lane >> 4) * 8;
    const float* coef = (n < 8) ? (al + n * 32) : (ar + (n - 8) * 32);
    int bc = (n < 8) ? n * 32 : (n - 8) * 32;
#pragma unroll
    for (int j = 0; j < 8; ++j) {
      int k = kb + j;
      float s = 0.f;
      for (int f = 0; f < 32; ++f) s += W1[k * 256 + bc + f] * coef[f];
      walar[(size_t)idx2 * 8 + j] = f2bf(s);
    }
  }
}

// MFMA GEMM, column-split: block = 32-row tile; wave w handles nf group
// {4w..4w+3} (64 cols). Wave 0 also carries walar (el/er) chain.
__global__ __launch_bounds__(256) void k_gemm1m(
    const float* __restrict__ x, const unsigned short* __restrict__ W1p,
    const unsigned short* __restrict__ walar,
    unsigned char* __restrict__ feat8, float* __restrict__ el,
    float* __restrict__ er, int n) {
  int w = threadIdx.x >> 6, lane = threadIdx.x & 63;
  int tile = blockIdx.x * 32;
  if (tile >= n) return;
  int r0 = lane & 15, kgrp = lane >> 4;
  int nf0 = w * 4;
  f32x4 acc[4][2];
  f32x4 accE[2];
#pragma unroll
  for (int nf = 0; nf < 4; ++nf)
#pragma unroll
    for (int mf = 0; mf < 2; ++mf) acc[nf][mf] = (f32x4){0.f, 0.f, 0.f, 0.f};
  accE[0] = (f32x4){0.f, 0.f, 0.f, 0.f};
  accE[1] = (f32x4){0.f, 0.f, 0.f, 0.f};

  for (int ks = 0; ks < 8; ++ks) {
    int kb = ks * 32 + kgrp * 8;
    short8 a0, a1;
    {
      int row = tile + r0;
      const float* p = x + (size_t)row * 256 + kb;
      float4 v0 = *reinterpret_cast<const float4*>(p);
      float4 v1 = *reinterpret_cast<const float4*>(p + 4);
      a0[0] = (short)f2bf(v0.x); a0[1] = (short)f2bf(v0.y);
      a0[2] = (short)f2bf(v0.z); a0[3] = (short)f2bf(v0.w);
      a0[4] = (short)f2bf(v1.x); a0[5] = (short)f2bf(v1.y);
      a0[6] = (short)f2bf(v1.z); a0[7] = (short)f2bf(v1.w);
    }
    {
      int row = tile + 16 + r0;
      if (row < n) {
        const float* p = x + (size_t)row * 256 + kb;
        float4 v0 = *reinterpret_cast<const float4*>(p);
        float4 v1 = *reinterpret_cast<const float4*>(p + 4);
        a1[0] = (short)f2bf(v0.x); a1[1] = (short)f2bf(v0.y);
        a1[2] = (short)f2bf(v0.z); a1[3] = (short)f2bf(v0.w);
        a1[4] = (short)f2bf(v1.x); a1[5] = (short)f2bf(v1.y);
        a1[6] = (short)f2bf(v1.z); a1[7] = (short)f2bf(v1.w);
      } else {
#pragma unroll
        for (int j = 0; j < 8; ++j) a1[j] = 0;
      }
    }
#pragma unroll
    for (int nf = 0; nf < 4; ++nf) {
      short8 b = *reinterpret_cast<const short8*>(
          W1p + ((size_t)((nf0 + nf) * 8 + ks) * 64 + lane) * 8);
      acc[nf][0] = __builtin_amdgcn_mfma_f32_16x16x32_bf16(a0, b, acc[nf][0], 0, 0, 0);
      acc[nf][1] = __builtin_amdgcn_mfma_f32_16x16x32_bf16(a1, b, acc[nf][1], 0, 0, 0);
    }
    if (w == 0) {
      short8 bE = *reinterpret_cast<const short8*>(
          walar + ((size_t)ks * 64 + lane) * 8);
      accE[0] = __builtin_amdgcn_mfma_f32_16x16x32_bf16(a0, bE, accE[0], 0, 0, 0);
      accE[1] = __builtin_amdgcn_mfma_f32_16x16x32_bf16(a1, bE, accE[1], 0, 0, 0);
    }
  }
  // store feat fp8
#pragma unroll
  for (int nf = 0; nf < 4; ++nf)
#pragma unroll
    for (int mf = 0; mf < 2; ++mf)
#pragma unroll
      for (int q = 0; q < 4; ++q) {
        int row = tile + mf * 16 + kgrp * 4 + q;
        if (row < n)
          feat8[(size_t)row * 256 + (nf0 + nf) * 16 + r0] = f2fp8(acc[nf][mf][q]);
      }
  // store el/er (wave 0): D col c=r0 (c<8 -> el head c, else er head c-8)
  if (w == 0) {
#pragma unroll
    for (int mf = 0; mf < 2; ++mf)
#pragma unroll
      for (int q = 0; q < 4; ++q) {
        int row = tile + mf * 16 + kgrp * 4 + q;
        if (row < n) {
          if (r0 < 8) el[(size_t)row * 8 + r0] = accE[mf][q];
          else        er[(size_t)row * 8 + (r0 - 8)] = accE[mf][q];
        }
      }
  }
}

// Wave per dst node. Lane l owns cols l*4..l*4+3 (head hh=l>>3).
// 8-edge groups: lane (e=l>>3, h=l&7) computes ee once. s via readlane
// (SGPR row base); packed fma on cvt_pk outputs.
__global__ __launch_bounds__(256) void k_agg1(
    const unsigned char* __restrict__ feat8, const float* __restrict__ el,
    const float* __restrict__ er, const int* __restrict__ offs,
    const unsigned short* __restrict__ csr, const float* __restrict__ b1,
    const float* __restrict__ W2, const float* __restrict__ al2,
    const float* __restrict__ ar2, float4* __restrict__ node4, int n) {
  int dn = blockIdx.x * 4 + (threadIdx.x >> 6);
  if (dn >= n) return;
  int l = threadIdx.x & 63;
  int hh = l >> 3;
  int h8 = l & 7;
  float erv = er[dn * 8 + h8];
  int beg = offs[dn], end = offs[dn + 1];
  f32x2 acc01 = {0.f, 0.f}, acc23 = {0.f, 0.f};
  float den = 0.f;
  int g = beg;
  for (; g + 8 <= end; g += 8) {
    int s_my = csr[g + (l >> 3)];
    float eev = lrelu_exp(el[s_my * 8 + h8] + erv);
#pragma unroll
    for (int e = 0; e < 8; ++e) {
      int s = __builtin_amdgcn_readlane(s_my, e * 8);  // uniform -> SGPR
      float ee = __shfl(eev, e * 8 + hh, 64);
      den += ee;
      const unsigned char* rowp = feat8 + (size_t)s * 256;  // scalar base
      unsigned int fv = *reinterpret_cast<const unsigned int*>(rowp + l * 4);
      f32x2 lo = __builtin_amdgcn_cvt_pk_f32_fp8(fv, false);
      f32x2 hi = __builtin_amdgcn_cvt_pk_f32_fp8(fv, true);
      f32x2 ee2 = {ee, ee};
      acc01 = ee2 * lo + acc01;
      acc23 = ee2 * hi + acc23;
    }
  }
  if (g < end) {
    int rem = end - g;
    int idx = g + (l >> 3);
    int s_t = csr[idx < end ? idx : end - 1];
    float ee_t = lrelu_exp(el[s_t * 8 + h8] + erv);
    for (int e = 0; e < rem; ++e) {
      int s = __builtin_amdgcn_readlane(s_t, e * 8);
      float ee = __shfl(ee_t, e * 8 + hh, 64);
      den += ee;
      const unsigned char* rowp = feat8 + (size_t)s * 256;
      unsigned int fv = *reinterpret_cast<const unsigned int*>(rowp + l * 4);
      f32x2 lo = __builtin_amdgcn_cvt_pk_f32_fp8(fv, false);
      f32x2 hi = __builtin_amdgcn_cvt_pk_f32_fp8(fv, true);
      f32x2 ee2 = {ee, ee};
      acc01 = ee2 * lo + acc01;
      acc23 = ee2 * hi + acc23;
    }
  }
  float4 bv = *reinterpret_cast<const float4*>(b1 + l * 4);
  float4 w2e = *reinterpret_cast<const float4*>(W2 + l * 8);
  float4 w2o = *reinterpret_cast<const float4*>(W2 + l * 8 + 4);
  float inv = 1.f / fmaxf(den, 1e-16f);
  float v0 = acc01[0] * inv + bv.x; v0 = v0 > 0.f ? v0 : expm1f(v0);
  float v1 = acc01[1] * inv + bv.y; v1 = v1 > 0.f ? v1 : expm1f(v1);
  float v2 = acc23[0] * inv + bv.z; v2 = v2 > 0.f ? v2 : expm1f(v2);
  float v3 = acc23[1] * inv + bv.w; v3 = v3 > 0.f ? v3 : expm1f(v3);
  float p0 = v0 * w2e.x + v1 * w2e.z + v2 * w2o.x + v3 * w2o.z;
  float p1 = v0 * w2e.y + v1 * w2e.w + v2 * w2o.y + v3 * w2o.w;
#pragma unroll
  for (int off = 32; off; off >>= 1) {
    p0 += __shfl_xor(p0, off, 64);
    p1 += __shfl_xor(p1, off, 64);
  }
  if (l == 0) {
    float e2 = p0 * al2[0] + p1 * al2[1];
    float r2 = p0 * ar2[0] + p1 * ar2[1];
    node4[dn] = make_float4(p0, p1, e2, r2);
  }
}

// Wave per dst node; single float4 gather per edge; fused log_softmax.
__global__ __launch_bounds__(256) void k_agg2(
    const float4* __restrict__ node4, const int* __restrict__ offs,
    const unsigned short* __restrict__ csr, const float* __restrict__ b2,
    float* __restrict__ out, int n) {
  int dn = blockIdx.x * 4 + (threadIdx.x >> 6);
  int l = threadIdx.x & 63;
  if (dn >= n) return;
  float erd = node4[dn].w;
  int beg = offs[dn], end = offs[dn + 1];
  float den = 0.f, a0 = 0.f, a1 = 0.f;
  for (int e = beg + l; e < end; e += 64) {
    int s = csr[e];
    float4 n4 = node4[s];
    float ev = n4.z + erd;
    ev = ev >= 0.f ? ev : 0.2f * ev;
    float ee = __expf(ev);
    den += ee;
    a0 = fmaf(ee, n4.x, a0);
    a1 = fmaf(ee, n4.y, a1);
  }
#pragma unroll
  for (int off = 32; off; off >>= 1) {
    den += __shfl_xor(den, off, 64);
    a0 += __shfl_xor(a0, off, 64);
    a1 += __shfl_xor(a1, off, 64);
  }
  if (l == 0) {
    float inv = 1.f / fmaxf(den, 1e-16f);
    float z0 = a0 * inv + b2[0];
    float z1 = a1 * inv + b2[1];
    float m = fmaxf(z0, z1);
    float lse = m + logf(__expf(z0 - m) + __expf(z1 - m));
    out[dn * 2 + 0] = z0 - lse;
    out[dn * 2 + 1] = z1 - lse;
  }
}

extern "C" void kernel_launch(void* const* d_in, const int* in_sizes, int n_in,
                              void* d_out, int out_size, void* d_ws,
                              size_t ws_size, hipStream_t stream) {
  const float* x   = (const float*)d_in[0];
  const int* esrc  = (const int*)d_in[1];
  const int* edst  = (const int*)d_in[2];
  const float* W1  = (const float*)d_in[3];
  const float* al1 = (const float*)d_in[4];
  const float* ar1 = (const float*)d_in[5];
  const float* b1  = (const float*)d_in[6];
  const float* W2  = (const float*)d_in[7];
  const float* al2 = (const float*)d_in[8];
  const float* ar2 = (const float*)d_in[9];
  const float* b2  = (const float*)d_in[10];
  float* out = (float*)d_out;

  size_t off = 0;
  auto alloc = [&](size_t bytes) {
    void* p = (char*)d_ws + off;
    off += (bytes + 255) & ~(size_t)255;
    return p;
  };
  unsigned char* feat8 = (unsigned char*)alloc((size_t)NN * 256);
  unsigned short* W1p  = (unsigned short*)alloc((size_t)16 * 8 * 64 * 8 * 2);
  unsigned short* walar = (unsigned short*)alloc((size_t)8 * 64 * 8 * 2);
  float* el1    = (float*)alloc((size_t)NN * 8 * 4);
  float* er1    = (float*)alloc((size_t)NN * 8 * 4);
  float4* node4 = (float4*)alloc((size_t)NN * 16);
  int* stage    = (int*)alloc((size_t)NBK * CAP * 4);
  unsigned short* csr = (unsigned short*)alloc((size_t)NE * 2);
  int* offs     = (int*)alloc((size_t)(NN + 1) * 4);
  int* cur      = (int*)alloc((size_t)NBK * 4);
  int* bbase    = (int*)alloc((size_t)(NBK + 1) * 4);

  hipMemsetAsync(cur, 0, (size_t)NBK * 4, stream);
  k_part<<<256, 256, 0, stream>>>(edst, esrc, cur, stage, NE);
  k_bscan<<<1, 256, 0, stream>>>(cur, bbase);
  k_build<<<NBK, 256, 0, stream>>>(stage, bbase, offs, csr, NN, NE);

  k_packw<<<34, 256, 0, stream>>>(W1, al1, ar1, W1p, walar);
  k_gemm1m<<<(NN + 31) / 32, 256, 0, stream>>>(x, W1p, walar, feat8, el1,
                                               er1, NN);
  k_agg1<<<(NN + 3) / 4, 256, 0, stream>>>(feat8, el1, er1, offs, csr, b1, W2,
                                           al2, ar2, node4, NN);
  k_agg2<<<(NN + 3) / 4, 256, 0, stream>>>(node4, offs, csr, b2, out, NN);
}

// Round 16
// 163.117 us; speedup vs baseline: 1.6406x; 1.1846x over previous
//
#include <hip/hip_runtime.h>
#include <hip/hip_fp8.h>

// GAT 2-layer. N=50000, E=1.6M (deg 32). L1: 256->8x32 (bf16 MFMA).
// feat stored FP8 e4m3; agg1 unpacks via HW cvt_pk_f32_fp8, packed-fma,
// readlane (SGPR row base) for src broadcast.
// gemm1m: block=32-row tile staged ONCE in LDS (bf16), 4 waves x 64-col.
// CSR build: deterministic atomic-free 2-pass partition (hist-matrix +
// per-bucket column scan) -> per-bucket LDS counting sort (512 thr).

#define NN 50000
#define NE 1600000
#define NBK 196      // coarse buckets of 256 nodes
#define NPB 512      // partition blocks
#define PCH 3125     // edges per partition block; 512 * 3125 = NE
#define CAP 16384    // stage ints per bucket (mean 8192, ~90 sigma margin)

typedef __attribute__((ext_vector_type(8))) short short8;
typedef __attribute__((ext_vector_type(4))) float f32x4;
typedef __attribute__((ext_vector_type(2))) float f32x2;

__device__ inline unsigned short f2bf(float f) {
  unsigned int u = __float_as_uint(f);
  unsigned int r = (u + 0x7fffu + ((u >> 16) & 1u)) >> 16;
  return (unsigned short)r;
}
__device__ inline unsigned char f2fp8(float f) {
  __hip_fp8_e4m3 q(f);
  return *reinterpret_cast<unsigned char*>(&q);
}
__device__ inline float lrelu_exp(float v) {
  v = v >= 0.f ? v : 0.2f * v;
  return __expf(v);
}

// pass 1: per-block LDS hist -> hmat[bucket][block].
__global__ __launch_bounds__(256) void k_hist2(const int* __restrict__ dst,
                                               int* __restrict__ hmat) {
  __shared__ int h[NBK];
  int tid = threadIdx.x, blk = blockIdx.x;
  for (int i = tid; i < NBK; i += 256) h[i] = 0;
  __syncthreads();
  int b0 = blk * PCH;
  for (int k = tid; k < PCH; k += 256)
    atomicAdd(&h[dst[b0 + k] >> 8], 1);
  __syncthreads();
  for (int i = tid; i < NBK; i += 256)
    hmat[(size_t)i * NPB + blk] = h[i];
}

// per-bucket exclusive scan over blocks; hmat <- bases, cur <- totals.
__global__ __launch_bounds__(512) void k_cscan(int* __restrict__ hmat,
                                               int* __restrict__ cur) {
  __shared__ int buf[NPB];
  int b = blockIdx.x, tid = threadIdx.x;
  int v = hmat[(size_t)b * NPB + tid];
  buf[tid] = v;
  __syncthreads();
  for (int off = 1; off < NPB; off <<= 1) {
    int t = (tid >= off) ? buf[tid - off] : 0;
    __syncthreads();
    buf[tid] += t;
    __syncthreads();
  }
  hmat[(size_t)b * NPB + tid] = buf[tid] - v;
  if (tid == NPB - 1) cur[b] = buf[tid];
}

// scan bucket totals (=cur) -> bbase[0..NBK].
__global__ __launch_bounds__(256) void k_bscan(const int* __restrict__ cur,
                                               int* __restrict__ bbase) {
  __shared__ int buf[256];
  int tid = threadIdx.x;
  int v = (tid < NBK) ? cur[tid] : 0;
  buf[tid] = v;
  __syncthreads();
  for (int off = 1; off < 256; off <<= 1) {
    int t = (tid >= off) ? buf[tid - off] : 0;
    __syncthreads();
    buf[tid] += t;
    __syncthreads();
  }
  if (tid < NBK) bbase[tid] = buf[tid] - v;
  if (tid == NBK - 1) bbase[NBK] = buf[tid];
}

// pass 2: LDS bucket-sort + copy-out at precomputed bases (no atomics).
// Entry = (bucket<<24)|((dst&255)<<16)|src.
__global__ __launch_bounds__(256) void k_part2(const int* __restrict__ dst,
                                               const int* __restrict__ src,
                                               const int* __restrict__ hmat,
                                               int* __restrict__ stage) {
  __shared__ int sbuf[PCH];
  __shared__ int h[NBK], scn[NBK], base[NBK], lofs[NBK];
  __shared__ int sc[256];
  int tid = threadIdx.x, blk = blockIdx.x;
  for (int i = tid; i < NBK; i += 256) { h[i] = 0; lofs[i] = 0; }
  __syncthreads();
  int b0 = blk * PCH;
  for (int k = tid; k < PCH; k += 256)
    atomicAdd(&h[dst[b0 + k] >> 8], 1);
  __syncthreads();
  int v = (tid < NBK) ? h[tid] : 0;
  sc[tid] = v;
  __syncthreads();
  for (int off = 1; off < 256; off <<= 1) {
    int t = (tid >= off) ? sc[tid - off] : 0;
    __syncthreads();
    sc[tid] += t;
    __syncthreads();
  }
  if (tid < NBK) {
    scn[tid] = sc[tid] - v;
    base[tid] = hmat[(size_t)tid * NPB + blk];
  }
  __syncthreads();
  for (int k = tid; k < PCH; k += 256) {
    int i = b0 + k;
    int d = dst[i];
    int b = d >> 8;
    int r = atomicAdd(&lofs[b], 1);
    sbuf[scn[b] + r] = (b << 24) | ((d & 255) << 16) | src[i];
  }
  __syncthreads();
  for (int i = tid; i < PCH; i += 256) {
    int e = sbuf[i];
    int b = (unsigned)e >> 24;
    stage[(size_t)b * CAP + base[b] + (i - scn[b])] = e;
  }
}

// per-bucket LDS counting sort: writes offs slice + places csr (ushort).
__global__ __launch_bounds__(512) void k_build(const int* __restrict__ stage,
                                               const int* __restrict__ bbase,
                                               int* __restrict__ offs,
                                               unsigned short* __restrict__ csr,
                                               int n, int E) {
  __shared__ int h[256], buf[256], cur[256];
  int b = blockIdx.x, tid = threadIdx.x;
  int beg = bbase[b];
  int tot = bbase[b + 1] - beg;
  const int* st = stage + (size_t)b * CAP;
  if (tid < 256) h[tid] = 0;
  __syncthreads();
  for (int k = tid; k < tot; k += 512)
    atomicAdd(&h[(st[k] >> 16) & 255], 1);
  __syncthreads();
  int v = (tid < 256) ? h[tid] : 0;
  if (tid < 256) buf[tid] = v;
  __syncthreads();
  for (int off = 1; off < 256; off <<= 1) {
    int t = (tid >= off && tid < 256) ? buf[tid - off] : 0;
    __syncthreads();
    if (tid < 256) buf[tid] += t;
    __syncthreads();
  }
  if (tid < 256) {
    int excl = buf[tid] - v;
    int node = b * 256 + tid;
    if (node < n) offs[node] = beg + excl;
    cur[tid] = excl;
  }
  if (b == 0 && tid == 0) offs[n] = E;
  __syncthreads();
  for (int k = tid; k < tot; k += 512) {
    int p = st[k];
    int r = atomicAdd(&cur[(p >> 16) & 255], 1);
    csr[beg + r] = (unsigned short)(p & 0xFFFF);
  }
}

// Pack W1 into MFMA B-fragment order (bf16) + walar = W1@[Ael|Aer] fragments.
__global__ __launch_bounds__(256) void k_packw(const float* __restrict__ W1,
                                               const float* __restrict__ al,
                                               const float* __restrict__ ar,
                                               unsigned short* __restrict__ W1p,
                                               unsigned short* __restrict__ walar) {
  int idx = blockIdx.x * 256 + threadIdx.x;
  if (idx < 8192) {  // W1p
    int nf = idx >> 9, rem = idx & 511;
    int ks = rem >> 6, lane = rem & 63;
    int n = nf * 16 + (lane & 15);
    int kb = ks * 32 + (lane >> 4) * 8;
#pragma unroll
    for (int j = 0; j < 8; ++j)
      W1p[(size_t)idx * 8 + j] = f2bf(W1[(kb + j) * 256 + n]);
  } else if (idx < 8192 + 512) {  // walar: [ks][lane] frag of 256x16
    int idx2 = idx - 8192;
    int ks = idx2 >> 6, lane = idx2 & 63;
    int n = lane & 15;
    int kb = ks * 32 + (lane >> 4) * 8;
    const float* coef = (n < 8) ? (al + n * 32) : (ar + (n - 8) * 32);
    int bc = (n < 8) ? n * 32 : (n - 8) * 32;
#pragma unroll
    for (int j = 0; j < 8; ++j) {
      int k = kb + j;
      float s = 0.f;
      for (int f = 0; f < 32; ++f) s += W1[k * 256 + bc + f] * coef[f];
      walar[(size_t)idx2 * 8 + j] = f2bf(s);
    }
  }
}

// MFMA GEMM, column-split + LDS-staged A: block = 32-row tile converted to
// bf16 in LDS once; wave w handles nf group {4w..4w+3}. Wave 0 adds walar.
__global__ __launch_bounds__(256) void k_gemm1m(
    const float* __restrict__ x, const unsigned short* __restrict__ W1p,
    const unsigned short* __restrict__ walar,
    unsigned char* __restrict__ feat8, float* __restrict__ el,
    float* __restrict__ er, int n) {
  __shared__ unsigned short xs[32][264];  // row stride 528B = 33x16B
  int w = threadIdx.x >> 6, lane = threadIdx.x & 63;
  int tile = blockIdx.x * 32;
  if (tile >= n) return;
  for (int idx = threadIdx.x; idx < 2048; idx += 256) {
    int r = idx >> 6, c4 = (idx & 63) * 4;
    int row = tile + r;
    float4 v = (row < n)
                   ? *reinterpret_cast<const float4*>(x + (size_t)row * 256 + c4)
                   : make_float4(0.f, 0.f, 0.f, 0.f);
    xs[r][c4 + 0] = f2bf(v.x);
    xs[r][c4 + 1] = f2bf(v.y);
    xs[r][c4 + 2] = f2bf(v.z);
    xs[r][c4 + 3] = f2bf(v.w);
  }
  __syncthreads();
  int r0 = lane & 15, kgrp = lane >> 4;
  int nf0 = w * 4;
  f32x4 acc[4][2];
  f32x4 accE[2];
#pragma unroll
  for (int nf = 0; nf < 4; ++nf)
#pragma unroll
    for (int mf = 0; mf < 2; ++mf) acc[nf][mf] = (f32x4){0.f, 0.f, 0.f, 0.f};
  accE[0] = (f32x4){0.f, 0.f, 0.f, 0.f};
  accE[1] = (f32x4){0.f, 0.f, 0.f, 0.f};

  for (int ks = 0; ks < 8; ++ks) {
    int kb = ks * 32 + kgrp * 8;
    short8 a0 = *reinterpret_cast<const short8*>(&xs[r0][kb]);
    short8 a1 = *reinterpret_cast<const short8*>(&xs[16 + r0][kb]);
#pragma unroll
    for (int nf = 0; nf < 4; ++nf) {
      short8 b = *reinterpret_cast<const short8*>(
          W1p + ((size_t)((nf0 + nf) * 8 + ks) * 64 + lane) * 8);
      acc[nf][0] = __builtin_amdgcn_mfma_f32_16x16x32_bf16(a0, b, acc[nf][0], 0, 0, 0);
      acc[nf][1] = __builtin_amdgcn_mfma_f32_16x16x32_bf16(a1, b, acc[nf][1], 0, 0, 0);
    }
    if (w == 0) {
      short8 bE = *reinterpret_cast<const short8*>(
          walar + ((size_t)ks * 64 + lane) * 8);
      accE[0] = __builtin_amdgcn_mfma_f32_16x16x32_bf16(a0, bE, accE[0], 0, 0, 0);
      accE[1] = __builtin_amdgcn_mfma_f32_16x16x32_bf16(a1, bE, accE[1], 0, 0, 0);
    }
  }
  // store feat fp8
#pragma unroll
  for (int nf = 0; nf < 4; ++nf)
#pragma unroll
    for (int mf = 0; mf < 2; ++mf)
#pragma unroll
      for (int q = 0; q < 4; ++q) {
        int row = tile + mf * 16 + kgrp * 4 + q;
        if (row < n)
          feat8[(size_t)row * 256 + (nf0 + nf) * 16 + r0] = f2fp8(acc[nf][mf][q]);
      }
  // store el/er (wave 0): D col c=r0 (c<8 -> el head c, else er head c-8)
  if (w == 0) {
#pragma unroll
    for (int mf = 0; mf < 2; ++mf)
#pragma unroll
      for (int q = 0; q < 4; ++q) {
        int row = tile + mf * 16 + kgrp * 4 + q;
        if (row < n) {
          if (r0 < 8) el[(size_t)row * 8 + r0] = accE[mf][q];
          else        er[(size_t)row * 8 + (r0 - 8)] = accE[mf][q];
        }
      }
  }
}

// Wave per dst node. Lane l owns cols l*4..l*4+3 (head hh=l>>3).
// 8-edge groups: lane (e=l>>3, h=l&7) computes ee once. s via readlane
// (SGPR row base); packed fma on cvt_pk outputs.
__global__ __launch_bounds__(256) void k_agg1(
    const unsigned char* __restrict__ feat8, const float* __restrict__ el,
    const float* __restrict__ er, const int* __restrict__ offs,
    const unsigned short* __restrict__ csr, const float* __restrict__ b1,
    const float* __restrict__ W2, const float* __restrict__ al2,
    const float* __restrict__ ar2, float4* __restrict__ node4, int n) {
  int dn = blockIdx.x * 4 + (threadIdx.x >> 6);
  if (dn >= n) return;
  int l = threadIdx.x & 63;
  int hh = l >> 3;
  int h8 = l & 7;
  float erv = er[dn * 8 + h8];
  int beg = offs[dn], end = offs[dn + 1];
  f32x2 acc01 = {0.f, 0.f}, acc23 = {0.f, 0.f};
  float den = 0.f;
  int g = beg;
  for (; g + 8 <= end; g += 8) {
    int s_my = csr[g + (l >> 3)];
    float eev = lrelu_exp(el[s_my * 8 + h8] + erv);
#pragma unroll
    for (int e = 0; e < 8; ++e) {
      int s = __builtin_amdgcn_readlane(s_my, e * 8);  // uniform -> SGPR
      float ee = __shfl(eev, e * 8 + hh, 64);
      den += ee;
      const unsigned char* rowp = feat8 + (size_t)s * 256;  // scalar base
      unsigned int fv = *reinterpret_cast<const unsigned int*>(rowp + l * 4);
      f32x2 lo = __builtin_amdgcn_cvt_pk_f32_fp8(fv, false);
      f32x2 hi = __builtin_amdgcn_cvt_pk_f32_fp8(fv, true);
      f32x2 ee2 = {ee, ee};
      acc01 = ee2 * lo + acc01;
      acc23 = ee2 * hi + acc23;
    }
  }
  if (g < end) {
    int rem = end - g;
    int idx = g + (l >> 3);
    int s_t = csr[idx < end ? idx : end - 1];
    float ee_t = lrelu_exp(el[s_t * 8 + h8] + erv);
    for (int e = 0; e < rem; ++e) {
      int s = __builtin_amdgcn_readlane(s_t, e * 8);
      float ee = __shfl(ee_t, e * 8 + hh, 64);
      den += ee;
      const unsigned char* rowp = feat8 + (size_t)s * 256;
      unsigned int fv = *reinterpret_cast<const unsigned int*>(rowp + l * 4);
      f32x2 lo = __builtin_amdgcn_cvt_pk_f32_fp8(fv, false);
      f32x2 hi = __builtin_amdgcn_cvt_pk_f32_fp8(fv, true);
      f32x2 ee2 = {ee, ee};
      acc01 = ee2 * lo + acc01;
      acc23 = ee2 * hi + acc23;
    }
  }
  float4 bv = *reinterpret_cast<const float4*>(b1 + l * 4);
  float4 w2e = *reinterpret_cast<const float4*>(W2 + l * 8);
  float4 w2o = *reinterpret_cast<const float4*>(W2 + l * 8 + 4);
  float inv = 1.f / fmaxf(den, 1e-16f);
  float v0 = acc01[0] * inv + bv.x; v0 = v0 > 0.f ? v0 : expm1f(v0);
  float v1 = acc01[1] * inv + bv.y; v1 = v1 > 0.f ? v1 : expm1f(v1);
  float v2 = acc23[0] * inv + bv.z; v2 = v2 > 0.f ? v2 : expm1f(v2);
  float v3 = acc23[1] * inv + bv.w; v3 = v3 > 0.f ? v3 : expm1f(v3);
  float p0 = v0 * w2e.x + v1 * w2e.z + v2 * w2o.x + v3 * w2o.z;
  float p1 = v0 * w2e.y + v1 * w2e.w + v2 * w2o.y + v3 * w2o.w;
#pragma unroll
  for (int off = 32; off; off >>= 1) {
    p0 += __shfl_xor(p0, off, 64);
    p1 += __shfl_xor(p1, off, 64);
  }
  if (l == 0) {
    float e2 = p0 * al2[0] + p1 * al2[1];
    float r2 = p0 * ar2[0] + p1 * ar2[1];
    node4[dn] = make_float4(p0, p1, e2, r2);
  }
}

// Wave per dst node; single float4 gather per edge; fused log_softmax.
__global__ __launch_bounds__(256) void k_agg2(
    const float4* __restrict__ node4, const int* __restrict__ offs,
    const unsigned short* __restrict__ csr, const float* __restrict__ b2,
    float* __restrict__ out, int n) {
  int dn = blockIdx.x * 4 + (threadIdx.x >> 6);
  int l = threadIdx.x & 63;
  if (dn >= n) return;
  float erd = node4[dn].w;
  int beg = offs[dn], end = offs[dn + 1];
  float den = 0.f, a0 = 0.f, a1 = 0.f;
  for (int e = beg + l; e < end; e += 64) {
    int s = csr[e];
    float4 n4 = node4[s];
    float ev = n4.z + erd;
    ev = ev >= 0.f ? ev : 0.2f * ev;
    float ee = __expf(ev);
    den += ee;
    a0 = fmaf(ee, n4.x, a0);
    a1 = fmaf(ee, n4.y, a1);
  }
#pragma unroll
  for (int off = 32; off; off >>= 1) {
    den += __shfl_xor(den, off, 64);
    a0 += __shfl_xor(a0, off, 64);
    a1 += __shfl_xor(a1, off, 64);
  }
  if (l == 0) {
    float inv = 1.f / fmaxf(den, 1e-16f);
    float z0 = a0 * inv + b2[0];
    float z1 = a1 * inv + b2[1];
    float m = fmaxf(z0, z1);
    float lse = m + logf(__expf(z0 - m) + __expf(z1 - m));
    out[dn * 2 + 0] = z0 - lse;
    out[dn * 2 + 1] = z1 - lse;
  }
}

extern "C" void kernel_launch(void* const* d_in, const int* in_sizes, int n_in,
                              void* d_out, int out_size, void* d_ws,
                              size_t ws_size, hipStream_t stream) {
  const float* x   = (const float*)d_in[0];
  const int* esrc  = (const int*)d_in[1];
  const int* edst  = (const int*)d_in[2];
  const float* W1  = (const float*)d_in[3];
  const float* al1 = (const float*)d_in[4];
  const float* ar1 = (const float*)d_in[5];
  const float* b1  = (const float*)d_in[6];
  const float* W2  = (const float*)d_in[7];
  const float* al2 = (const float*)d_in[8];
  const float* ar2 = (const float*)d_in[9];
  const float* b2  = (const float*)d_in[10];
  float* out = (float*)d_out;

  size_t off = 0;
  auto alloc = [&](size_t bytes) {
    void* p = (char*)d_ws + off;
    off += (bytes + 255) & ~(size_t)255;
    return p;
  };
  unsigned char* feat8 = (unsigned char*)alloc((size_t)NN * 256);
  unsigned short* W1p  = (unsigned short*)alloc((size_t)16 * 8 * 64 * 8 * 2);
  unsigned short* walar = (unsigned short*)alloc((size_t)8 * 64 * 8 * 2);
  float* el1    = (float*)alloc((size_t)NN * 8 * 4);
  float* er1    = (float*)alloc((size_t)NN * 8 * 4);
  float4* node4 = (float4*)alloc((size_t)NN * 16);
  int* stage    = (int*)alloc((size_t)NBK * CAP * 4);
  int* hmat     = (int*)alloc((size_t)NBK * NPB * 4);
  unsigned short* csr = (unsigned short*)alloc((size_t)NE * 2);
  int* offs     = (int*)alloc((size_t)(NN + 1) * 4);
  int* cur      = (int*)alloc((size_t)NBK * 4);
  int* bbase    = (int*)alloc((size_t)(NBK + 1) * 4);

  k_hist2<<<NPB, 256, 0, stream>>>(edst, hmat);
  k_cscan<<<NBK, NPB, 0, stream>>>(hmat, cur);
  k_bscan<<<1, 256, 0, stream>>>(cur, bbase);
  k_part2<<<NPB, 256, 0, stream>>>(edst, esrc, hmat, stage);
  k_build<<<NBK, 512, 0, stream>>>(stage, bbase, offs, csr, NN, NE);

  k_packw<<<34, 256, 0, stream>>>(W1, al1, ar1, W1p, walar);
  k_gemm1m<<<(NN + 31) / 32, 256, 0, stream>>>(x, W1p, walar, feat8, el1,
                                               er1, NN);
  k_agg1<<<(NN + 3) / 4, 256, 0, stream>>>(feat8, el1, er1, offs, csr, b1, W2,
                                           al2, ar2, node4, NN);
  k_agg2<<<(NN + 3) / 4, 256, 0, stream>>>(node4, offs, csr, b2, out, NN);
}

// Round 17
// 159.746 us; speedup vs baseline: 1.6752x; 1.0211x over previous
//
#include <hip/hip_runtime.h>
#include <hip/hip_fp8.h>

// GAT 2-layer. N=50000, E=1.6M (deg 32). L1: 256->8x32 (bf16 MFMA).
// feat stored FP8 e4m3; agg1 unpacks via HW cvt_pk_f32_fp8, packed-fma,
// readlane (SGPR row base) for src broadcast.
// gemm1m: block=32-row tile staged ONCE in LDS (bf16), 4 waves x 64-col.
// CSR: cap-strided (offs + deg arrays, no bscan). Build: atomic-free
// 2-pass partition (hist-matrix + column scan) -> per-bucket LDS sort.
// agg2: 2 nodes per wave (32-lane halves).

#define NN 50000
#define NE 1600000
#define NBK 196      // coarse buckets of 256 nodes
#define NPB 512      // partition blocks
#define PCH 3125     // edges per partition block; 512 * 3125 = NE
#define CAP 16384    // stage/csr slots per bucket (mean 8192, ~90 sigma)

typedef __attribute__((ext_vector_type(8))) short short8;
typedef __attribute__((ext_vector_type(4))) float f32x4;
typedef __attribute__((ext_vector_type(2))) float f32x2;

__device__ inline unsigned short f2bf(float f) {
  unsigned int u = __float_as_uint(f);
  unsigned int r = (u + 0x7fffu + ((u >> 16) & 1u)) >> 16;
  return (unsigned short)r;
}
__device__ inline unsigned char f2fp8(float f) {
  __hip_fp8_e4m3 q(f);
  return *reinterpret_cast<unsigned char*>(&q);
}
__device__ inline float lrelu_exp(float v) {
  v = v >= 0.f ? v : 0.2f * v;
  return __expf(v);
}

// pass 1: per-block LDS hist -> hmat[bucket][block].
__global__ __launch_bounds__(256) void k_hist2(const int* __restrict__ dst,
                                               int* __restrict__ hmat) {
  __shared__ int h[NBK];
  int tid = threadIdx.x, blk = blockIdx.x;
  for (int i = tid; i < NBK; i += 256) h[i] = 0;
  __syncthreads();
  int b0 = blk * PCH;
  for (int k = tid; k < PCH; k += 256)
    atomicAdd(&h[dst[b0 + k] >> 8], 1);
  __syncthreads();
  for (int i = tid; i < NBK; i += 256)
    hmat[(size_t)i * NPB + blk] = h[i];
}

// per-bucket exclusive scan over blocks; hmat <- bases, cur <- totals.
__global__ __launch_bounds__(512) void k_cscan(int* __restrict__ hmat,
                                               int* __restrict__ cur) {
  __shared__ int buf[NPB];
  int b = blockIdx.x, tid = threadIdx.x;
  int v = hmat[(size_t)b * NPB + tid];
  buf[tid] = v;
  __syncthreads();
  for (int off = 1; off < NPB; off <<= 1) {
    int t = (tid >= off) ? buf[tid - off] : 0;
    __syncthreads();
    buf[tid] += t;
    __syncthreads();
  }
  hmat[(size_t)b * NPB + tid] = buf[tid] - v;
  if (tid == NPB - 1) cur[b] = buf[tid];
}

// pass 2: LDS bucket-sort + copy-out at precomputed bases (no atomics on
// global cursors). dst stashed in LDS to avoid 2nd global read.
// Entry = (bucket<<24)|((dst&255)<<16)|src.
__global__ __launch_bounds__(256) void k_part2(const int* __restrict__ dst,
                                               const int* __restrict__ src,
                                               const int* __restrict__ hmat,
                                               int* __restrict__ stage) {
  __shared__ int sbuf[PCH];
  __shared__ int dbuf[PCH];
  __shared__ int h[NBK], scn[NBK], base[NBK], lofs[NBK];
  __shared__ int sc[256];
  int tid = threadIdx.x, blk = blockIdx.x;
  for (int i = tid; i < NBK; i += 256) { h[i] = 0; lofs[i] = 0; }
  __syncthreads();
  int b0 = blk * PCH;
  for (int k = tid; k < PCH; k += 256) {
    int d = dst[b0 + k];
    dbuf[k] = d;
    atomicAdd(&h[d >> 8], 1);
  }
  __syncthreads();
  int v = (tid < NBK) ? h[tid] : 0;
  sc[tid] = v;
  __syncthreads();
  for (int off = 1; off < 256; off <<= 1) {
    int t = (tid >= off) ? sc[tid - off] : 0;
    __syncthreads();
    sc[tid] += t;
    __syncthreads();
  }
  if (tid < NBK) {
    scn[tid] = sc[tid] - v;
    base[tid] = hmat[(size_t)tid * NPB + blk];
  }
  __syncthreads();
  for (int k = tid; k < PCH; k += 256) {
    int d = dbuf[k];
    int b = d >> 8;
    int r = atomicAdd(&lofs[b], 1);
    sbuf[scn[b] + r] = (b << 24) | ((d & 255) << 16) | src[b0 + k];
  }
  __syncthreads();
  for (int i = tid; i < PCH; i += 256) {
    int e = sbuf[i];
    int b = (unsigned)e >> 24;
    stage[(size_t)b * CAP + base[b] + (i - scn[b])] = e;
  }
}

// per-bucket LDS counting sort: offs (cap-strided) + deg + csr (ushort).
__global__ __launch_bounds__(512) void k_build(const int* __restrict__ stage,
                                               const int* __restrict__ tots,
                                               int* __restrict__ offs,
                                               int* __restrict__ deg,
                                               unsigned short* __restrict__ csr,
                                               int n) {
  __shared__ int h[256], buf[256], cur[256];
  int b = blockIdx.x, tid = threadIdx.x;
  int tot = tots[b];
  const int* st = stage + (size_t)b * CAP;
  unsigned short* cs = csr + (size_t)b * CAP;
  if (tid < 256) h[tid] = 0;
  __syncthreads();
  for (int k = tid; k < tot; k += 512)
    atomicAdd(&h[(st[k] >> 16) & 255], 1);
  __syncthreads();
  int v = (tid < 256) ? h[tid] : 0;
  if (tid < 256) buf[tid] = v;
  __syncthreads();
  for (int off = 1; off < 256; off <<= 1) {
    int t = (tid >= off && tid < 256) ? buf[tid - off] : 0;
    __syncthreads();
    if (tid < 256) buf[tid] += t;
    __syncthreads();
  }
  if (tid < 256) {
    int excl = buf[tid] - v;
    int node = b * 256 + tid;
    if (node < n) {
      offs[node] = b * CAP + excl;
      deg[node] = v;
    }
    cur[tid] = excl;
  }
  __syncthreads();
  for (int k = tid; k < tot; k += 512) {
    int p = st[k];
    int r = atomicAdd(&cur[(p >> 16) & 255], 1);
    cs[r] = (unsigned short)(p & 0xFFFF);
  }
}

// Pack W1 into MFMA B-fragment order (bf16) + walar = W1@[Ael|Aer] fragments.
__global__ __launch_bounds__(256) void k_packw(const float* __restrict__ W1,
                                               const float* __restrict__ al,
                                               const float* __restrict__ ar,
                                               unsigned short* __restrict__ W1p,
                                               unsigned short* __restrict__ walar) {
  int idx = blockIdx.x * 256 + threadIdx.x;
  if (idx < 8192) {  // W1p
    int nf = idx >> 9, rem = idx & 511;
    int ks = rem >> 6, lane = rem & 63;
    int n = nf * 16 + (lane & 15);
    int kb = ks * 32 + (lane >> 4) * 8;
#pragma unroll
    for (int j = 0; j < 8; ++j)
      W1p[(size_t)idx * 8 + j] = f2bf(W1[(kb + j) * 256 + n]);
  } else if (idx < 8192 + 512) {  // walar: [ks][lane] frag of 256x16
    int idx2 = idx - 8192;
    int ks = idx2 >> 6, lane = idx2 & 63;
    int n = lane & 15;
    int kb = ks * 32 + (lane >> 4) * 8;
    const float* coef = (n < 8) ? (al + n * 32) : (ar + (n - 8) * 32);
    int bc = (n < 8) ? n * 32 : (n - 8) * 32;
#pragma unroll
    for (int j = 0; j < 8; ++j) {
      int k = kb + j;
      float s = 0.f;
      for (int f = 0; f < 32; ++f) s += W1[k * 256 + bc + f] * coef[f];
      walar[(size_t)idx2 * 8 + j] = f2bf(s);
    }
  }
}

// MFMA GEMM, column-split + LDS-staged A: block = 32-row tile converted to
// bf16 in LDS once; wave w handles nf group {4w..4w+3}. Wave 0 adds walar.
__global__ __launch_bounds__(256) void k_gemm1m(
    const float* __restrict__ x, const unsigned short* __restrict__ W1p,
    const unsigned short* __restrict__ walar,
    unsigned char* __restrict__ feat8, float* __restrict__ el,
    float* __restrict__ er, int n) {
  __shared__ unsigned short xs[32][264];  // row stride 528B = 33x16B
  int w = threadIdx.x >> 6, lane = threadIdx.x & 63;
  int tile = blockIdx.x * 32;
  if (tile >= n) return;
  for (int idx = threadIdx.x; idx < 2048; idx += 256) {
    int r = idx >> 6, c4 = (idx & 63) * 4;
    int row = tile + r;
    float4 v = (row < n)
                   ? *reinterpret_cast<const float4*>(x + (size_t)row * 256 + c4)
                   : make_float4(0.f, 0.f, 0.f, 0.f);
    xs[r][c4 + 0] = f2bf(v.x);
    xs[r][c4 + 1] = f2bf(v.y);
    xs[r][c4 + 2] = f2bf(v.z);
    xs[r][c4 + 3] = f2bf(v.w);
  }
  __syncthreads();
  int r0 = lane & 15, kgrp = lane >> 4;
  int nf0 = w * 4;
  f32x4 acc[4][2];
  f32x4 accE[2];
#pragma unroll
  for (int nf = 0; nf < 4; ++nf)
#pragma unroll
    for (int mf = 0; mf < 2; ++mf) acc[nf][mf] = (f32x4){0.f, 0.f, 0.f, 0.f};
  accE[0] = (f32x4){0.f, 0.f, 0.f, 0.f};
  accE[1] = (f32x4){0.f, 0.f, 0.f, 0.f};

  for (int ks = 0; ks < 8; ++ks) {
    int kb = ks * 32 + kgrp * 8;
    short8 a0 = *reinterpret_cast<const short8*>(&xs[r0][kb]);
    short8 a1 = *reinterpret_cast<const short8*>(&xs[16 + r0][kb]);
#pragma unroll
    for (int nf = 0; nf < 4; ++nf) {
      short8 b = *reinterpret_cast<const short8*>(
          W1p + ((size_t)((nf0 + nf) * 8 + ks) * 64 + lane) * 8);
      acc[nf][0] = __builtin_amdgcn_mfma_f32_16x16x32_bf16(a0, b, acc[nf][0], 0, 0, 0);
      acc[nf][1] = __builtin_amdgcn_mfma_f32_16x16x32_bf16(a1, b, acc[nf][1], 0, 0, 0);
    }
    if (w == 0) {
      short8 bE = *reinterpret_cast<const short8*>(
          walar + ((size_t)ks * 64 + lane) * 8);
      accE[0] = __builtin_amdgcn_mfma_f32_16x16x32_bf16(a0, bE, accE[0], 0, 0, 0);
      accE[1] = __builtin_amdgcn_mfma_f32_16x16x32_bf16(a1, bE, accE[1], 0, 0, 0);
    }
  }
  // store feat fp8
#pragma unroll
  for (int nf = 0; nf < 4; ++nf)
#pragma unroll
    for (int mf = 0; mf < 2; ++mf)
#pragma unroll
      for (int q = 0; q < 4; ++q) {
        int row = tile + mf * 16 + kgrp * 4 + q;
        if (row < n)
          feat8[(size_t)row * 256 + (nf0 + nf) * 16 + r0] = f2fp8(acc[nf][mf][q]);
      }
  // store el/er (wave 0): D col c=r0 (c<8 -> el head c, else er head c-8)
  if (w == 0) {
#pragma unroll
    for (int mf = 0; mf < 2; ++mf)
#pragma unroll
      for (int q = 0; q < 4; ++q) {
        int row = tile + mf * 16 + kgrp * 4 + q;
        if (row < n) {
          if (r0 < 8) el[(size_t)row * 8 + r0] = accE[mf][q];
          else        er[(size_t)row * 8 + (r0 - 8)] = accE[mf][q];
        }
      }
  }
}

// Wave per dst node. Lane l owns cols l*4..l*4+3 (head hh=l>>3).
// 8-edge groups: lane (e=l>>3, h=l&7) computes ee once. s via readlane
// (SGPR row base); packed fma on cvt_pk outputs.
__global__ __launch_bounds__(256) void k_agg1(
    const unsigned char* __restrict__ feat8, const float* __restrict__ el,
    const float* __restrict__ er, const int* __restrict__ offs,
    const int* __restrict__ deg, const unsigned short* __restrict__ csr,
    const float* __restrict__ b1, const float* __restrict__ W2,
    const float* __restrict__ al2, const float* __restrict__ ar2,
    float4* __restrict__ node4, int n) {
  int dn = blockIdx.x * 4 + (threadIdx.x >> 6);
  if (dn >= n) return;
  int l = threadIdx.x & 63;
  int hh = l >> 3;
  int h8 = l & 7;
  float erv = er[dn * 8 + h8];
  int beg = offs[dn], end = beg + deg[dn];
  f32x2 acc01 = {0.f, 0.f}, acc23 = {0.f, 0.f};
  float den = 0.f;
  int g = beg;
  for (; g + 8 <= end; g += 8) {
    int s_my = csr[g + (l >> 3)];
    float eev = lrelu_exp(el[s_my * 8 + h8] + erv);
#pragma unroll
    for (int e = 0; e < 8; ++e) {
      int s = __builtin_amdgcn_readlane(s_my, e * 8);  // uniform -> SGPR
      float ee = __shfl(eev, e * 8 + hh, 64);
      den += ee;
      const unsigned char* rowp = feat8 + (size_t)s * 256;  // scalar base
      unsigned int fv = *reinterpret_cast<const unsigned int*>(rowp + l * 4);
      f32x2 lo = __builtin_amdgcn_cvt_pk_f32_fp8(fv, false);
      f32x2 hi = __builtin_amdgcn_cvt_pk_f32_fp8(fv, true);
      f32x2 ee2 = {ee, ee};
      acc01 = ee2 * lo + acc01;
      acc23 = ee2 * hi + acc23;
    }
  }
  if (g < end) {
    int rem = end - g;
    int idx = g + (l >> 3);
    int s_t = csr[idx < end ? idx : end - 1];
    float ee_t = lrelu_exp(el[s_t * 8 + h8] + erv);
    for (int e = 0; e < rem; ++e) {
      int s = __builtin_amdgcn_readlane(s_t, e * 8);
      float ee = __shfl(ee_t, e * 8 + hh, 64);
      den += ee;
      const unsigned char* rowp = feat8 + (size_t)s * 256;
      unsigned int fv = *reinterpret_cast<const unsigned int*>(rowp + l * 4);
      f32x2 lo = __builtin_amdgcn_cvt_pk_f32_fp8(fv, false);
      f32x2 hi = __builtin_amdgcn_cvt_pk_f32_fp8(fv, true);
      f32x2 ee2 = {ee, ee};
      acc01 = ee2 * lo + acc01;
      acc23 = ee2 * hi + acc23;
    }
  }
  float4 bv = *reinterpret_cast<const float4*>(b1 + l * 4);
  float4 w2e = *reinterpret_cast<const float4*>(W2 + l * 8);
  float4 w2o = *reinterpret_cast<const float4*>(W2 + l * 8 + 4);
  float inv = 1.f / fmaxf(den, 1e-16f);
  float v0 = acc01[0] * inv + bv.x; v0 = v0 > 0.f ? v0 : expm1f(v0);
  float v1 = acc01[1] * inv + bv.y; v1 = v1 > 0.f ? v1 : expm1f(v1);
  float v2 = acc23[0] * inv + bv.z; v2 = v2 > 0.f ? v2 : expm1f(v2);
  float v3 = acc23[1] * inv + bv.w; v3 = v3 > 0.f ? v3 : expm1f(v3);
  float p0 = v0 * w2e.x + v1 * w2e.z + v2 * w2o.x + v3 * w2o.z;
  float p1 = v0 * w2e.y + v1 * w2e.w + v2 * w2o.y + v3 * w2o.w;
#pragma unroll
  for (int off = 32; off; off >>= 1) {
    p0 += __shfl_xor(p0, off, 64);
    p1 += __shfl_xor(p1, off, 64);
  }
  if (l == 0) {
    float e2 = p0 * al2[0] + p1 * al2[1];
    float r2 = p0 * ar2[0] + p1 * ar2[1];
    node4[dn] = make_float4(p0, p1, e2, r2);
  }
}

// 2 nodes per wave (32-lane halves); float4 gather/edge; fused log_softmax.
__global__ __launch_bounds__(256) void k_agg2(
    const float4* __restrict__ node4, const int* __restrict__ offs,
    const int* __restrict__ deg, const unsigned short* __restrict__ csr,
    const float* __restrict__ b2, float* __restrict__ out, int n) {
  int dn = blockIdx.x * 8 + (threadIdx.x >> 5);
  int l = threadIdx.x & 31;
  if (dn >= n) return;
  float erd = node4[dn].w;
  int beg = offs[dn], end = beg + deg[dn];
  float den = 0.f, a0 = 0.f, a1 = 0.f;
  for (int e = beg + l; e < end; e += 32) {
    int s = csr[e];
    float4 n4 = node4[s];
    float ev = n4.z + erd;
    ev = ev >= 0.f ? ev : 0.2f * ev;
    float ee = __expf(ev);
    den += ee;
    a0 = fmaf(ee, n4.x, a0);
    a1 = fmaf(ee, n4.y, a1);
  }
#pragma unroll
  for (int off = 16; off; off >>= 1) {
    den += __shfl_xor(den, off, 32);
    a0 += __shfl_xor(a0, off, 32);
    a1 += __shfl_xor(a1, off, 32);
  }
  if (l == 0) {
    float inv = 1.f / fmaxf(den, 1e-16f);
    float z0 = a0 * inv + b2[0];
    float z1 = a1 * inv + b2[1];
    float m = fmaxf(z0, z1);
    float lse = m + logf(__expf(z0 - m) + __expf(z1 - m));
    out[dn * 2 + 0] = z0 - lse;
    out[dn * 2 + 1] = z1 - lse;
  }
}

extern "C" void kernel_launch(void* const* d_in, const int* in_sizes, int n_in,
                              void* d_out, int out_size, void* d_ws,
                              size_t ws_size, hipStream_t stream) {
  const float* x   = (const float*)d_in[0];
  const int* esrc  = (const int*)d_in[1];
  const int* edst  = (const int*)d_in[2];
  const float* W1  = (const float*)d_in[3];
  const float* al1 = (const float*)d_in[4];
  const float* ar1 = (const float*)d_in[5];
  const float* b1  = (const float*)d_in[6];
  const float* W2  = (const float*)d_in[7];
  const float* al2 = (const float*)d_in[8];
  const float* ar2 = (const float*)d_in[9];
  const float* b2  = (const float*)d_in[10];
  float* out = (float*)d_out;

  size_t off = 0;
  auto alloc = [&](size_t bytes) {
    void* p = (char*)d_ws + off;
    off += (bytes + 255) & ~(size_t)255;
    return p;
  };
  unsigned char* feat8 = (unsigned char*)alloc((size_t)NN * 256);
  unsigned short* W1p  = (unsigned short*)alloc((size_t)16 * 8 * 64 * 8 * 2);
  unsigned short* walar = (unsigned short*)alloc((size_t)8 * 64 * 8 * 2);
  float* el1    = (float*)alloc((size_t)NN * 8 * 4);
  float* er1    = (float*)alloc((size_t)NN * 8 * 4);
  float4* node4 = (float4*)alloc((size_t)NN * 16);
  int* stage    = (int*)alloc((size_t)NBK * CAP * 4);
  int* hmat     = (int*)alloc((size_t)NBK * NPB * 4);
  unsigned short* csr = (unsigned short*)alloc((size_t)NBK * CAP * 2);
  int* offs     = (int*)alloc((size_t)NN * 4);
  int* deg      = (int*)alloc((size_t)NN * 4);
  int* cur      = (int*)alloc((size_t)NBK * 4);

  k_hist2<<<NPB, 256, 0, stream>>>(edst, hmat);
  k_cscan<<<NBK, NPB, 0, stream>>>(hmat, cur);
  k_part2<<<NPB, 256, 0, stream>>>(edst, esrc, hmat, stage);
  k_build<<<NBK, 512, 0, stream>>>(stage, cur, offs, deg, csr, NN);

  k_packw<<<34, 256, 0, stream>>>(W1, al1, ar1, W1p, walar);
  k_gemm1m<<<(NN + 31) / 32, 256, 0, stream>>>(x, W1p, walar, feat8, el1,
                                               er1, NN);
  k_agg1<<<(NN + 3) / 4, 256, 0, stream>>>(feat8, el1, er1, offs, deg, csr, b1,
                                           W2, al2, ar2, node4, NN);
  k_agg2<<<(NN + 7) / 8, 256, 0, stream>>>(node4, offs, deg, csr, b2, out, NN);
}

// Round 18
// 155.322 us; speedup vs baseline: 1.7229x; 1.0285x over previous
//
#include <hip/hip_runtime.h>
#include <hip/hip_fp8.h>

// GAT 2-layer. N=50000, E=1.6M (deg 32). L1: 256->8x32 (bf16 MFMA).
// feat stored FP8 e4m3; agg1 unpacks via HW cvt_pk_f32_fp8, packed-fma,
// readlane (SGPR row base) for src broadcast. (off,deg) packed int2.
// gemm1m: block=32-row tile staged ONCE in LDS (bf16), 4 waves x 64-col.
// CSR: cap-strided. Build: atomic-free 2-pass partition (1024 blocks) ->
// per-bucket LDS counting sort. agg2: 2 nodes per wave.

#define NN 50000
#define NE 1600000
#define NBK 196      // coarse buckets of 256 nodes
#define NPB 1024     // partition blocks
#define PCH 1563     // edges per partition block; 1024*1563 >= NE
#define CAP 16384    // stage/csr slots per bucket (mean 8192, ~90 sigma)

typedef __attribute__((ext_vector_type(8))) short short8;
typedef __attribute__((ext_vector_type(4))) float f32x4;
typedef __attribute__((ext_vector_type(2))) float f32x2;

__device__ inline unsigned short f2bf(float f) {
  unsigned int u = __float_as_uint(f);
  unsigned int r = (u + 0x7fffu + ((u >> 16) & 1u)) >> 16;
  return (unsigned short)r;
}
__device__ inline unsigned char f2fp8(float f) {
  __hip_fp8_e4m3 q(f);
  return *reinterpret_cast<unsigned char*>(&q);
}
__device__ inline float lrelu_exp(float v) {
  v = v >= 0.f ? v : 0.2f * v;
  return __expf(v);
}

// pass 1: per-block LDS hist -> hmat[bucket][block].
__global__ __launch_bounds__(256) void k_hist2(const int* __restrict__ dst,
                                               int* __restrict__ hmat, int E) {
  __shared__ int h[NBK];
  int tid = threadIdx.x, blk = blockIdx.x;
  for (int i = tid; i < NBK; i += 256) h[i] = 0;
  __syncthreads();
  int b0 = blk * PCH;
  int tot = min(PCH, E - b0);
  for (int k = tid; k < tot; k += 256)
    atomicAdd(&h[dst[b0 + k] >> 8], 1);
  __syncthreads();
  for (int i = tid; i < NBK; i += 256)
    hmat[(size_t)i * NPB + blk] = h[i];
}

// per-bucket exclusive scan over blocks; hmat <- bases, cur <- totals.
__global__ __launch_bounds__(1024) void k_cscan(int* __restrict__ hmat,
                                                int* __restrict__ cur) {
  __shared__ int buf[NPB];
  int b = blockIdx.x, tid = threadIdx.x;
  int v = hmat[(size_t)b * NPB + tid];
  buf[tid] = v;
  __syncthreads();
  for (int off = 1; off < NPB; off <<= 1) {
    int t = (tid >= off) ? buf[tid - off] : 0;
    __syncthreads();
    buf[tid] += t;
    __syncthreads();
  }
  hmat[(size_t)b * NPB + tid] = buf[tid] - v;
  if (tid == NPB - 1) cur[b] = buf[tid];
}

// pass 2: LDS bucket-sort + copy-out at precomputed bases (no global
// atomics). dst stashed in LDS. Entry = (bucket<<24)|((dst&255)<<16)|src.
__global__ __launch_bounds__(256) void k_part2(const int* __restrict__ dst,
                                               const int* __restrict__ src,
                                               const int* __restrict__ hmat,
                                               int* __restrict__ stage, int E) {
  __shared__ int sbuf[PCH];
  __shared__ int dbuf[PCH];
  __shared__ int h[NBK], scn[NBK], base[NBK], lofs[NBK];
  __shared__ int sc[256];
  int tid = threadIdx.x, blk = blockIdx.x;
  for (int i = tid; i < NBK; i += 256) { h[i] = 0; lofs[i] = 0; }
  __syncthreads();
  int b0 = blk * PCH;
  int tot = min(PCH, E - b0);
  for (int k = tid; k < tot; k += 256) {
    int d = dst[b0 + k];
    dbuf[k] = d;
    atomicAdd(&h[d >> 8], 1);
  }
  __syncthreads();
  int v = (tid < NBK) ? h[tid] : 0;
  sc[tid] = v;
  __syncthreads();
  for (int off = 1; off < 256; off <<= 1) {
    int t = (tid >= off) ? sc[tid - off] : 0;
    __syncthreads();
    sc[tid] += t;
    __syncthreads();
  }
  if (tid < NBK) {
    scn[tid] = sc[tid] - v;
    base[tid] = hmat[(size_t)tid * NPB + blk];
  }
  __syncthreads();
  for (int k = tid; k < tot; k += 256) {
    int d = dbuf[k];
    int b = d >> 8;
    int r = atomicAdd(&lofs[b], 1);
    sbuf[scn[b] + r] = (b << 24) | ((d & 255) << 16) | src[b0 + k];
  }
  __syncthreads();
  for (int i = tid; i < tot; i += 256) {
    int e = sbuf[i];
    int b = (unsigned)e >> 24;
    stage[(size_t)b * CAP + base[b] + (i - scn[b])] = e;
  }
}

// per-bucket LDS counting sort: od (int2: cap-strided off, deg) + csr.
__global__ __launch_bounds__(512) void k_build(const int* __restrict__ stage,
                                               const int* __restrict__ tots,
                                               int2* __restrict__ od,
                                               unsigned short* __restrict__ csr,
                                               int n) {
  __shared__ int h[256], buf[256], cur[256];
  int b = blockIdx.x, tid = threadIdx.x;
  int tot = tots[b];
  const int* st = stage + (size_t)b * CAP;
  unsigned short* cs = csr + (size_t)b * CAP;
  if (tid < 256) h[tid] = 0;
  __syncthreads();
  for (int k = tid; k < tot; k += 512)
    atomicAdd(&h[(st[k] >> 16) & 255], 1);
  __syncthreads();
  int v = (tid < 256) ? h[tid] : 0;
  if (tid < 256) buf[tid] = v;
  __syncthreads();
  for (int off = 1; off < 256; off <<= 1) {
    int t = (tid >= off && tid < 256) ? buf[tid - off] : 0;
    __syncthreads();
    if (tid < 256) buf[tid] += t;
    __syncthreads();
  }
  if (tid < 256) {
    int excl = buf[tid] - v;
    int node = b * 256 + tid;
    if (node < n) od[node] = make_int2(b * CAP + excl, v);
    cur[tid] = excl;
  }
  __syncthreads();
  for (int k = tid; k < tot; k += 512) {
    int p = st[k];
    int r = atomicAdd(&cur[(p >> 16) & 255], 1);
    cs[r] = (unsigned short)(p & 0xFFFF);
  }
}

// Pack W1 into MFMA B-fragment order (bf16) + walar = W1@[Ael|Aer] fragments.
__global__ __launch_bounds__(256) void k_packw(const float* __restrict__ W1,
                                               const float* __restrict__ al,
                                               const float* __restrict__ ar,
                                               unsigned short* __restrict__ W1p,
                                               unsigned short* __restrict__ walar) {
  int idx = blockIdx.x * 256 + threadIdx.x;
  if (idx < 8192) {  // W1p
    int nf = idx >> 9, rem = idx & 511;
    int ks = rem >> 6, lane = rem & 63;
    int n = nf * 16 + (lane & 15);
    int kb = ks * 32 + (lane >> 4) * 8;
#pragma unroll
    for (int j = 0; j < 8; ++j)
      W1p[(size_t)idx * 8 + j] = f2bf(W1[(kb + j) * 256 + n]);
  } else if (idx < 8192 + 512) {  // walar: [ks][lane] frag of 256x16
    int idx2 = idx - 8192;
    int ks = idx2 >> 6, lane = idx2 & 63;
    int n = lane & 15;
    int kb = ks * 32 + (lane >> 4) * 8;
    const float* coef = (n < 8) ? (al + n * 32) : (ar + (n - 8) * 32);
    int bc = (n < 8) ? n * 32 : (n - 8) * 32;
#pragma unroll
    for (int j = 0; j < 8; ++j) {
      int k = kb + j;
      float s = 0.f;
      for (int f = 0; f < 32; ++f) s += W1[k * 256 + bc + f] * coef[f];
      walar[(size_t)idx2 * 8 + j] = f2bf(s);
    }
  }
}

// MFMA GEMM, column-split + LDS-staged A: block = 32-row tile converted to
// bf16 in LDS once; wave w handles nf group {4w..4w+3}. Wave 0 adds walar.
__global__ __launch_bounds__(256) void k_gemm1m(
    const float* __restrict__ x, const unsigned short* __restrict__ W1p,
    const unsigned short* __restrict__ walar,
    unsigned char* __restrict__ feat8, float* __restrict__ el,
    float* __restrict__ er, int n) {
  __shared__ unsigned short xs[32][264];  // row stride 528B = 33x16B
  int w = threadIdx.x >> 6, lane = threadIdx.x & 63;
  int tile = blockIdx.x * 32;
  if (tile >= n) return;
  for (int idx = threadIdx.x; idx < 2048; idx += 256) {
    int r = idx >> 6, c4 = (idx & 63) * 4;
    int row = tile + r;
    float4 v = (row < n)
                   ? *reinterpret_cast<const float4*>(x + (size_t)row * 256 + c4)
                   : make_float4(0.f, 0.f, 0.f, 0.f);
    xs[r][c4 + 0] = f2bf(v.x);
    xs[r][c4 + 1] = f2bf(v.y);
    xs[r][c4 + 2] = f2bf(v.z);
    xs[r][c4 + 3] = f2bf(v.w);
  }
  __syncthreads();
  int r0 = lane & 15, kgrp = lane >> 4;
  int nf0 = w * 4;
  f32x4 acc[4][2];
  f32x4 accE[2];
#pragma unroll
  for (int nf = 0; nf < 4; ++nf)
#pragma unroll
    for (int mf = 0; mf < 2; ++mf) acc[nf][mf] = (f32x4){0.f, 0.f, 0.f, 0.f};
  accE[0] = (f32x4){0.f, 0.f, 0.f, 0.f};
  accE[1] = (f32x4){0.f, 0.f, 0.f, 0.f};

  for (int ks = 0; ks < 8; ++ks) {
    int kb = ks * 32 + kgrp * 8;
    short8 a0 = *reinterpret_cast<const short8*>(&xs[r0][kb]);
    short8 a1 = *reinterpret_cast<const short8*>(&xs[16 + r0][kb]);
#pragma unroll
    for (int nf = 0; nf < 4; ++nf) {
      short8 b = *reinterpret_cast<const short8*>(
          W1p + ((size_t)((nf0 + nf) * 8 + ks) * 64 + lane) * 8);
      acc[nf][0] = __builtin_amdgcn_mfma_f32_16x16x32_bf16(a0, b, acc[nf][0], 0, 0, 0);
      acc[nf][1] = __builtin_amdgcn_mfma_f32_16x16x32_bf16(a1, b, acc[nf][1], 0, 0, 0);
    }
    if (w == 0) {
      short8 bE = *reinterpret_cast<const short8*>(
          walar + ((size_t)ks * 64 + lane) * 8);
      accE[0] = __builtin_amdgcn_mfma_f32_16x16x32_bf16(a0, bE, accE[0], 0, 0, 0);
      accE[1] = __builtin_amdgcn_mfma_f32_16x16x32_bf16(a1, bE, accE[1], 0, 0, 0);
    }
  }
  // store feat fp8
#pragma unroll
  for (int nf = 0; nf < 4; ++nf)
#pragma unroll
    for (int mf = 0; mf < 2; ++mf)
#pragma unroll
      for (int q = 0; q < 4; ++q) {
        int row = tile + mf * 16 + kgrp * 4 + q;
        if (row < n)
          feat8[(size_t)row * 256 + (nf0 + nf) * 16 + r0] = f2fp8(acc[nf][mf][q]);
      }
  // store el/er (wave 0): D col c=r0 (c<8 -> el head c, else er head c-8)
  if (w == 0) {
#pragma unroll
    for (int mf = 0; mf < 2; ++mf)
#pragma unroll
      for (int q = 0; q < 4; ++q) {
        int row = tile + mf * 16 + kgrp * 4 + q;
        if (row < n) {
          if (r0 < 8) el[(size_t)row * 8 + r0] = accE[mf][q];
          else        er[(size_t)row * 8 + (r0 - 8)] = accE[mf][q];
        }
      }
  }
}

// Wave per dst node. Lane l owns cols l*4..l*4+3 (head hh=l>>3).
// 8-edge groups: lane (e=l>>3, h=l&7) computes ee once. s via readlane
// (SGPR row base); packed fma on cvt_pk outputs. (off,deg) = one int2 load.
__global__ __launch_bounds__(256) void k_agg1(
    const unsigned char* __restrict__ feat8, const float* __restrict__ el,
    const float* __restrict__ er, const int2* __restrict__ od,
    const unsigned short* __restrict__ csr, const float* __restrict__ b1,
    const float* __restrict__ W2, const float* __restrict__ al2,
    const float* __restrict__ ar2, float4* __restrict__ node4, int n) {
  int dn = blockIdx.x * 4 + (threadIdx.x >> 6);
  if (dn >= n) return;
  int l = threadIdx.x & 63;
  int hh = l >> 3;
  int h8 = l & 7;
  float erv = er[dn * 8 + h8];
  int2 o2 = od[dn];
  int beg = o2.x, end = o2.x + o2.y;
  f32x2 acc01 = {0.f, 0.f}, acc23 = {0.f, 0.f};
  float den = 0.f;
  int g = beg;
  for (; g + 8 <= end; g += 8) {
    int s_my = csr[g + (l >> 3)];
    float eev = lrelu_exp(el[s_my * 8 + h8] + erv);
#pragma unroll
    for (int e = 0; e < 8; ++e) {
      int s = __builtin_amdgcn_readlane(s_my, e * 8);  // uniform -> SGPR
      float ee = __shfl(eev, e * 8 + hh, 64);
      den += ee;
      const unsigned char* rowp = feat8 + (size_t)s * 256;  // scalar base
      unsigned int fv = *reinterpret_cast<const unsigned int*>(rowp + l * 4);
      f32x2 lo = __builtin_amdgcn_cvt_pk_f32_fp8(fv, false);
      f32x2 hi = __builtin_amdgcn_cvt_pk_f32_fp8(fv, true);
      f32x2 ee2 = {ee, ee};
      acc01 = ee2 * lo + acc01;
      acc23 = ee2 * hi + acc23;
    }
  }
  if (g < end) {
    int rem = end - g;
    int idx = g + (l >> 3);
    int s_t = csr[idx < end ? idx : end - 1];
    float ee_t = lrelu_exp(el[s_t * 8 + h8] + erv);
    for (int e = 0; e < rem; ++e) {
      int s = __builtin_amdgcn_readlane(s_t, e * 8);
      float ee = __shfl(ee_t, e * 8 + hh, 64);
      den += ee;
      const unsigned char* rowp = feat8 + (size_t)s * 256;
      unsigned int fv = *reinterpret_cast<const unsigned int*>(rowp + l * 4);
      f32x2 lo = __builtin_amdgcn_cvt_pk_f32_fp8(fv, false);
      f32x2 hi = __builtin_amdgcn_cvt_pk_f32_fp8(fv, true);
      f32x2 ee2 = {ee, ee};
      acc01 = ee2 * lo + acc01;
      acc23 = ee2 * hi + acc23;
    }
  }
  float4 bv = *reinterpret_cast<const float4*>(b1 + l * 4);
  float4 w2e = *reinterpret_cast<const float4*>(W2 + l * 8);
  float4 w2o = *reinterpret_cast<const float4*>(W2 + l * 8 + 4);
  float inv = 1.f / fmaxf(den, 1e-16f);
  float v0 = acc01[0] * inv + bv.x; v0 = v0 > 0.f ? v0 : expm1f(v0);
  float v1 = acc01[1] * inv + bv.y; v1 = v1 > 0.f ? v1 : expm1f(v1);
  float v2 = acc23[0] * inv + bv.z; v2 = v2 > 0.f ? v2 : expm1f(v2);
  float v3 = acc23[1] * inv + bv.w; v3 = v3 > 0.f ? v3 : expm1f(v3);
  float p0 = v0 * w2e.x + v1 * w2e.z + v2 * w2o.x + v3 * w2o.z;
  float p1 = v0 * w2e.y + v1 * w2e.w + v2 * w2o.y + v3 * w2o.w;
#pragma unroll
  for (int off = 32; off; off >>= 1) {
    p0 += __shfl_xor(p0, off, 64);
    p1 += __shfl_xor(p1, off, 64);
  }
  if (l == 0) {
    float e2 = p0 * al2[0] + p1 * al2[1];
    float r2 = p0 * ar2[0] + p1 * ar2[1];
    node4[dn] = make_float4(p0, p1, e2, r2);
  }
}

// 2 nodes per wave (32-lane halves); float4 gather/edge; fused log_softmax.
__global__ __launch_bounds__(256) void k_agg2(
    const float4* __restrict__ node4, const int2* __restrict__ od,
    const unsigned short* __restrict__ csr, const float* __restrict__ b2,
    float* __restrict__ out, int n) {
  int dn = blockIdx.x * 8 + (threadIdx.x >> 5);
  int l = threadIdx.x & 31;
  if (dn >= n) return;
  float erd = node4[dn].w;
  int2 o2 = od[dn];
  int beg = o2.x, end = o2.x + o2.y;
  float den = 0.f, a0 = 0.f, a1 = 0.f;
  for (int e = beg + l; e < end; e += 32) {
    int s = csr[e];
    float4 n4 = node4[s];
    float ev = n4.z + erd;
    ev = ev >= 0.f ? ev : 0.2f * ev;
    float ee = __expf(ev);
    den += ee;
    a0 = fmaf(ee, n4.x, a0);
    a1 = fmaf(ee, n4.y, a1);
  }
#pragma unroll
  for (int off = 16; off; off >>= 1) {
    den += __shfl_xor(den, off, 32);
    a0 += __shfl_xor(a0, off, 32);
    a1 += __shfl_xor(a1, off, 32);
  }
  if (l == 0) {
    float inv = 1.f / fmaxf(den, 1e-16f);
    float z0 = a0 * inv + b2[0];
    float z1 = a1 * inv + b2[1];
    float m = fmaxf(z0, z1);
    float lse = m + logf(__expf(z0 - m) + __expf(z1 - m));
    out[dn * 2 + 0] = z0 - lse;
    out[dn * 2 + 1] = z1 - lse;
  }
}

extern "C" void kernel_launch(void* const* d_in, const int* in_sizes, int n_in,
                              void* d_out, int out_size, void* d_ws,
                              size_t ws_size, hipStream_t stream) {
  const float* x   = (const float*)d_in[0];
  const int* esrc  = (const int*)d_in[1];
  const int* edst  = (const int*)d_in[2];
  const float* W1  = (const float*)d_in[3];
  const float* al1 = (const float*)d_in[4];
  const float* ar1 = (const float*)d_in[5];
  const float* b1  = (const float*)d_in[6];
  const float* W2  = (const float*)d_in[7];
  const float* al2 = (const float*)d_in[8];
  const float* ar2 = (const float*)d_in[9];
  const float* b2  = (const float*)d_in[10];
  float* out = (float*)d_out;

  size_t off = 0;
  auto alloc = [&](size_t bytes) {
    void* p = (char*)d_ws + off;
    off += (bytes + 255) & ~(size_t)255;
    return p;
  };
  unsigned char* feat8 = (unsigned char*)alloc((size_t)NN * 256);
  unsigned short* W1p  = (unsigned short*)alloc((size_t)16 * 8 * 64 * 8 * 2);
  unsigned short* walar = (unsigned short*)alloc((size_t)8 * 64 * 8 * 2);
  float* el1    = (float*)alloc((size_t)NN * 8 * 4);
  float* er1    = (float*)alloc((size_t)NN * 8 * 4);
  float4* node4 = (float4*)alloc((size_t)NN * 16);
  int* stage    = (int*)alloc((size_t)NBK * CAP * 4);
  int* hmat     = (int*)alloc((size_t)NBK * NPB * 4);
  unsigned short* csr = (unsigned short*)alloc((size_t)NBK * CAP * 2);
  int2* od      = (int2*)alloc((size_t)NN * 8);
  int* cur      = (int*)alloc((size_t)NBK * 4);

  k_hist2<<<NPB, 256, 0, stream>>>(edst, hmat, NE);
  k_cscan<<<NBK, NPB, 0, stream>>>(hmat, cur);
  k_part2<<<NPB, 256, 0, stream>>>(edst, esrc, hmat, stage, NE);
  k_build<<<NBK, 512, 0, stream>>>(stage, cur, od, csr, NN);

  k_packw<<<34, 256, 0, stream>>>(W1, al1, ar1, W1p, walar);
  k_gemm1m<<<(NN + 31) / 32, 256, 0, stream>>>(x, W1p, walar, feat8, el1,
                                               er1, NN);
  k_agg1<<<(NN + 3) / 4, 256, 0, stream>>>(feat8, el1, er1, od, csr, b1,
                                           W2, al2, ar2, node4, NN);
  k_agg2<<<(NN + 7) / 8, 256, 0, stream>>>(node4, od, csr, b2, out, NN);
}

// Round 20
// 154.023 us; speedup vs baseline: 1.7374x; 1.0084x over previous
//
#include <hip/hip_runtime.h>
#include <hip/hip_fp8.h>

// GAT 2-layer. N=50000, E=1.6M (deg 32). L1: 256->8x32 (bf16 MFMA).
// feat stored FP8 e4m3; agg1 (round-18 proven): 8-edge groups, readlane
// SGPR row base, cvt_pk + packed-fma, (off,deg) int2.
// gemm1m: LDS-staged A, 4 waves x 64-col, walar el/er chain.
// CSR: cap-strided, atomic-free 2-pass partition -> per-bucket LDS sort.
// agg2: 16-lane quarter-wave per node (the single delta under test).

#define NN 50000
#define NE 1600000
#define NBK 196      // coarse buckets of 256 nodes
#define NPB 1024     // partition blocks
#define PCH 1563     // edges per partition block; 1024*1563 >= NE
#define CAP 16384    // stage/csr slots per bucket (mean 8192, ~90 sigma)

typedef __attribute__((ext_vector_type(8))) short short8;
typedef __attribute__((ext_vector_type(4))) float f32x4;
typedef __attribute__((ext_vector_type(2))) float f32x2;

__device__ inline unsigned short f2bf(float f) {
  unsigned int u = __float_as_uint(f);
  unsigned int r = (u + 0x7fffu + ((u >> 16) & 1u)) >> 16;
  return (unsigned short)r;
}
__device__ inline unsigned char f2fp8(float f) {
  __hip_fp8_e4m3 q(f);
  return *reinterpret_cast<unsigned char*>(&q);
}
__device__ inline float lrelu_exp(float v) {
  v = v >= 0.f ? v : 0.2f * v;
  return __expf(v);
}

// pass 1: per-block LDS hist -> hmat[bucket][block].
__global__ __launch_bounds__(256) void k_hist2(const int* __restrict__ dst,
                                               int* __restrict__ hmat, int E) {
  __shared__ int h[NBK];
  int tid = threadIdx.x, blk = blockIdx.x;
  for (int i = tid; i < NBK; i += 256) h[i] = 0;
  __syncthreads();
  int b0 = blk * PCH;
  int tot = min(PCH, E - b0);
  for (int k = tid; k < tot; k += 256)
    atomicAdd(&h[dst[b0 + k] >> 8], 1);
  __syncthreads();
  for (int i = tid; i < NBK; i += 256)
    hmat[(size_t)i * NPB + blk] = h[i];
}

// per-bucket exclusive scan over blocks; hmat <- bases, cur <- totals.
__global__ __launch_bounds__(1024) void k_cscan(int* __restrict__ hmat,
                                                int* __restrict__ cur) {
  __shared__ int buf[NPB];
  int b = blockIdx.x, tid = threadIdx.x;
  int v = hmat[(size_t)b * NPB + tid];
  buf[tid] = v;
  __syncthreads();
  for (int off = 1; off < NPB; off <<= 1) {
    int t = (tid >= off) ? buf[tid - off] : 0;
    __syncthreads();
    buf[tid] += t;
    __syncthreads();
  }
  hmat[(size_t)b * NPB + tid] = buf[tid] - v;
  if (tid == NPB - 1) cur[b] = buf[tid];
}

// pass 2: LDS bucket-sort + copy-out at precomputed bases (no global
// atomics). dst stashed in LDS. Entry = (bucket<<24)|((dst&255)<<16)|src.
__global__ __launch_bounds__(256) void k_part2(const int* __restrict__ dst,
                                               const int* __restrict__ src,
                                               const int* __restrict__ hmat,
                                               int* __restrict__ stage, int E) {
  __shared__ int sbuf[PCH];
  __shared__ int dbuf[PCH];
  __shared__ int h[NBK], scn[NBK], base[NBK], lofs[NBK];
  __shared__ int sc[256];
  int tid = threadIdx.x, blk = blockIdx.x;
  for (int i = tid; i < NBK; i += 256) { h[i] = 0; lofs[i] = 0; }
  __syncthreads();
  int b0 = blk * PCH;
  int tot = min(PCH, E - b0);
  for (int k = tid; k < tot; k += 256) {
    int d = dst[b0 + k];
    dbuf[k] = d;
    atomicAdd(&h[d >> 8], 1);
  }
  __syncthreads();
  int v = (tid < NBK) ? h[tid] : 0;
  sc[tid] = v;
  __syncthreads();
  for (int off = 1; off < 256; off <<= 1) {
    int t = (tid >= off) ? sc[tid - off] : 0;
    __syncthreads();
    sc[tid] += t;
    __syncthreads();
  }
  if (tid < NBK) {
    scn[tid] = sc[tid] - v;
    base[tid] = hmat[(size_t)tid * NPB + blk];
  }
  __syncthreads();
  for (int k = tid; k < tot; k += 256) {
    int d = dbuf[k];
    int b = d >> 8;
    int r = atomicAdd(&lofs[b], 1);
    sbuf[scn[b] + r] = (b << 24) | ((d & 255) << 16) | src[b0 + k];
  }
  __syncthreads();
  for (int i = tid; i < tot; i += 256) {
    int e = sbuf[i];
    int b = (unsigned)e >> 24;
    stage[(size_t)b * CAP + base[b] + (i - scn[b])] = e;
  }
}

// per-bucket LDS counting sort: od (int2: cap-strided off, deg) + csr.
__global__ __launch_bounds__(512) void k_build(const int* __restrict__ stage,
                                               const int* __restrict__ tots,
                                               int2* __restrict__ od,
                                               unsigned short* __restrict__ csr,
                                               int n) {
  __shared__ int h[256], buf[256], cur[256];
  int b = blockIdx.x, tid = threadIdx.x;
  int tot = tots[b];
  const int* st = stage + (size_t)b * CAP;
  unsigned short* cs = csr + (size_t)b * CAP;
  if (tid < 256) h[tid] = 0;
  __syncthreads();
  for (int k = tid; k < tot; k += 512)
    atomicAdd(&h[(st[k] >> 16) & 255], 1);
  __syncthreads();
  int v = (tid < 256) ? h[tid] : 0;
  if (tid < 256) buf[tid] = v;
  __syncthreads();
  for (int off = 1; off < 256; off <<= 1) {
    int t = (tid >= off && tid < 256) ? buf[tid - off] : 0;
    __syncthreads();
    if (tid < 256) buf[tid] += t;
    __syncthreads();
  }
  if (tid < 256) {
    int excl = buf[tid] - v;
    int node = b * 256 + tid;
    if (node < n) od[node] = make_int2(b * CAP + excl, v);
    cur[tid] = excl;
  }
  __syncthreads();
  for (int k = tid; k < tot; k += 512) {
    int p = st[k];
    int r = atomicAdd(&cur[(p >> 16) & 255], 1);
    cs[r] = (unsigned short)(p & 0xFFFF);
  }
}

// Pack W1 into MFMA B-fragment order (bf16) + walar = W1@[Ael|Aer] fragments.
__global__ __launch_bounds__(256) void k_packw(const float* __restrict__ W1,
                                               const float* __restrict__ al,
                                               const float* __restrict__ ar,
                                               unsigned short* __restrict__ W1p,
                                               unsigned short* __restrict__ walar) {
  int idx = blockIdx.x * 256 + threadIdx.x;
  if (idx < 8192) {  // W1p
    int nf = idx >> 9, rem = idx & 511;
    int ks = rem >> 6, lane = rem & 63;
    int n = nf * 16 + (lane & 15);
    int kb = ks * 32 + (lane >> 4) * 8;
#pragma unroll
    for (int j = 0; j < 8; ++j)
      W1p[(size_t)idx * 8 + j] = f2bf(W1[(kb + j) * 256 + n]);
  } else if (idx < 8192 + 512) {  // walar: [ks][lane] frag of 256x16
    int idx2 = idx - 8192;
    int ks = idx2 >> 6, lane = idx2 & 63;
    int n = lane & 15;
    int kb = ks * 32 + (lane >> 4) * 8;
    const float* coef = (n < 8) ? (al + n * 32) : (ar + (n - 8) * 32);
    int bc = (n < 8) ? n * 32 : (n - 8) * 32;
#pragma unroll
    for (int j = 0; j < 8; ++j) {
      int k = kb + j;
      float s = 0.f;
      for (int f = 0; f < 32; ++f) s += W1[k * 256 + bc + f] * coef[f];
      walar[(size_t)idx2 * 8 + j] = f2bf(s);
    }
  }
}

// MFMA GEMM, column-split + LDS-staged A: block = 32-row tile converted to
// bf16 in LDS once; wave w handles nf group {4w..4w+3}. Wave 0 adds walar.
__global__ __launch_bounds__(256) void k_gemm1m(
    const float* __restrict__ x, const unsigned short* __restrict__ W1p,
    const unsigned short* __restrict__ walar,
    unsigned char* __restrict__ feat8, float* __restrict__ el,
    float* __restrict__ er, int n) {
  __shared__ unsigned short xs[32][264];  // row stride 528B = 33x16B
  int w = threadIdx.x >> 6, lane = threadIdx.x & 63;
  int tile = blockIdx.x * 32;
  if (tile >= n) return;
  for (int idx = threadIdx.x; idx < 2048; idx += 256) {
    int r = idx >> 6, c4 = (idx & 63) * 4;
    int row = tile + r;
    float4 v = (row < n)
                   ? *reinterpret_cast<const float4*>(x + (size_t)row * 256 + c4)
                   : make_float4(0.f, 0.f, 0.f, 0.f);
    xs[r][c4 + 0] = f2bf(v.x);
    xs[r][c4 + 1] = f2bf(v.y);
    xs[r][c4 + 2] = f2bf(v.z);
    xs[r][c4 + 3] = f2bf(v.w);
  }
  __syncthreads();
  int r0 = lane & 15, kgrp = lane >> 4;
  int nf0 = w * 4;
  f32x4 acc[4][2];
  f32x4 accE[2];
#pragma unroll
  for (int nf = 0; nf < 4; ++nf)
#pragma unroll
    for (int mf = 0; mf < 2; ++mf) acc[nf][mf] = (f32x4){0.f, 0.f, 0.f, 0.f};
  accE[0] = (f32x4){0.f, 0.f, 0.f, 0.f};
  accE[1] = (f32x4){0.f, 0.f, 0.f, 0.f};

  for (int ks = 0; ks < 8; ++ks) {
    int kb = ks * 32 + kgrp * 8;
    short8 a0 = *reinterpret_cast<const short8*>(&xs[r0][kb]);
    short8 a1 = *reinterpret_cast<const short8*>(&xs[16 + r0][kb]);
#pragma unroll
    for (int nf = 0; nf < 4; ++nf) {
      short8 b = *reinterpret_cast<const short8*>(
          W1p + ((size_t)((nf0 + nf) * 8 + ks) * 64 + lane) * 8);
      acc[nf][0] = __builtin_amdgcn_mfma_f32_16x16x32_bf16(a0, b, acc[nf][0], 0, 0, 0);
      acc[nf][1] = __builtin_amdgcn_mfma_f32_16x16x32_bf16(a1, b, acc[nf][1], 0, 0, 0);
    }
    if (w == 0) {
      short8 bE = *reinterpret_cast<const short8*>(
          walar + ((size_t)ks * 64 + lane) * 8);
      accE[0] = __builtin_amdgcn_mfma_f32_16x16x32_bf16(a0, bE, accE[0], 0, 0, 0);
      accE[1] = __builtin_amdgcn_mfma_f32_16x16x32_bf16(a1, bE, accE[1], 0, 0, 0);
    }
  }
  // store feat fp8
#pragma unroll
  for (int nf = 0; nf < 4; ++nf)
#pragma unroll
    for (int mf = 0; mf < 2; ++mf)
#pragma unroll
      for (int q = 0; q < 4; ++q) {
        int row = tile + mf * 16 + kgrp * 4 + q;
        if (row < n)
          feat8[(size_t)row * 256 + (nf0 + nf) * 16 + r0] = f2fp8(acc[nf][mf][q]);
      }
  // store el/er (wave 0): D col c=r0 (c<8 -> el head c, else er head c-8)
  if (w == 0) {
#pragma unroll
    for (int mf = 0; mf < 2; ++mf)
#pragma unroll
      for (int q = 0; q < 4; ++q) {
        int row = tile + mf * 16 + kgrp * 4 + q;
        if (row < n) {
          if (r0 < 8) el[(size_t)row * 8 + r0] = accE[mf][q];
          else        er[(size_t)row * 8 + (r0 - 8)] = accE[mf][q];
        }
      }
  }
}

// Wave per dst node. Lane l owns cols l*4..l*4+3 (head hh=l>>3).
// 8-edge groups: lane (e=l>>3, h=l&7) computes ee once. s via readlane
// (SGPR row base); packed fma on cvt_pk outputs. (off,deg) = one int2 load.
__global__ __launch_bounds__(256) void k_agg1(
    const unsigned char* __restrict__ feat8, const float* __restrict__ el,
    const float* __restrict__ er, const int2* __restrict__ od,
    const unsigned short* __restrict__ csr, const float* __restrict__ b1,
    const float* __restrict__ W2, const float* __restrict__ al2,
    const float* __restrict__ ar2, float4* __restrict__ node4, int n) {
  int dn = blockIdx.x * 4 + (threadIdx.x >> 6);
  if (dn >= n) return;
  int l = threadIdx.x & 63;
  int hh = l >> 3;
  int h8 = l & 7;
  float erv = er[dn * 8 + h8];
  int2 o2 = od[dn];
  int beg = o2.x, end = o2.x + o2.y;
  f32x2 acc01 = {0.f, 0.f}, acc23 = {0.f, 0.f};
  float den = 0.f;
  int g = beg;
  for (; g + 8 <= end; g += 8) {
    int s_my = csr[g + (l >> 3)];
    float eev = lrelu_exp(el[s_my * 8 + h8] + erv);
#pragma unroll
    for (int e = 0; e < 8; ++e) {
      int s = __builtin_amdgcn_readlane(s_my, e * 8);  // uniform -> SGPR
      float ee = __shfl(eev, e * 8 + hh, 64);
      den += ee;
      const unsigned char* rowp = feat8 + (size_t)s * 256;  // scalar base
      unsigned int fv = *reinterpret_cast<const unsigned int*>(rowp + l * 4);
      f32x2 lo = __builtin_amdgcn_cvt_pk_f32_fp8(fv, false);
      f32x2 hi = __builtin_amdgcn_cvt_pk_f32_fp8(fv, true);
      f32x2 ee2 = {ee, ee};
      acc01 = ee2 * lo + acc01;
      acc23 = ee2 * hi + acc23;
    }
  }
  if (g < end) {
    int rem = end - g;
    int idx = g + (l >> 3);
    int s_t = csr[idx < end ? idx : end - 1];
    float ee_t = lrelu_exp(el[s_t * 8 + h8] + erv);
    for (int e = 0; e < rem; ++e) {
      int s = __builtin_amdgcn_readlane(s_t, e * 8);
      float ee = __shfl(ee_t, e * 8 + hh, 64);
      den += ee;
      const unsigned char* rowp = feat8 + (size_t)s * 256;
      unsigned int fv = *reinterpret_cast<const unsigned int*>(rowp + l * 4);
      f32x2 lo = __builtin_amdgcn_cvt_pk_f32_fp8(fv, false);
      f32x2 hi = __builtin_amdgcn_cvt_pk_f32_fp8(fv, true);
      f32x2 ee2 = {ee, ee};
      acc01 = ee2 * lo + acc01;
      acc23 = ee2 * hi + acc23;
    }
  }
  float4 bv = *reinterpret_cast<const float4*>(b1 + l * 4);
  float4 w2e = *reinterpret_cast<const float4*>(W2 + l * 8);
  float4 w2o = *reinterpret_cast<const float4*>(W2 + l * 8 + 4);
  float inv = 1.f / fmaxf(den, 1e-16f);
  float v0 = acc01[0] * inv + bv.x; v0 = v0 > 0.f ? v0 : expm1f(v0);
  float v1 = acc01[1] * inv + bv.y; v1 = v1 > 0.f ? v1 : expm1f(v1);
  float v2 = acc23[0] * inv + bv.z; v2 = v2 > 0.f ? v2 : expm1f(v2);
  float v3 = acc23[1] * inv + bv.w; v3 = v3 > 0.f ? v3 : expm1f(v3);
  float p0 = v0 * w2e.x + v1 * w2e.z + v2 * w2o.x + v3 * w2o.z;
  float p1 = v0 * w2e.y + v1 * w2e.w + v2 * w2o.y + v3 * w2o.w;
#pragma unroll
  for (int off = 32; off; off >>= 1) {
    p0 += __shfl_xor(p0, off, 64);
    p1 += __shfl_xor(p1, off, 64);
  }
  if (l == 0) {
    float e2 = p0 * al2[0] + p1 * al2[1];
    float r2 = p0 * ar2[0] + p1 * ar2[1];
    node4[dn] = make_float4(p0, p1, e2, r2);
  }
}

// 16-lane quarter-wave per node; float4 gather/edge; fused log_softmax.
__global__ __launch_bounds__(256) void k_agg2(
    const float4* __restrict__ node4, const int2* __restrict__ od,
    const unsigned short* __restrict__ csr, const float* __restrict__ b2,
    float* __restrict__ out, int n) {
  int dn = blockIdx.x * 16 + (threadIdx.x >> 4);
  int l = threadIdx.x & 15;
  if (dn >= n) return;
  float erd = node4[dn].w;
  int2 o2 = od[dn];
  int beg = o2.x, end = o2.x + o2.y;
  float den = 0.f, a0 = 0.f, a1 = 0.f;
  for (int e = beg + l; e < end; e += 16) {
    int s = csr[e];
    float4 n4 = node4[s];
    float ev = n4.z + erd;
    ev = ev >= 0.f ? ev : 0.2f * ev;
    float ee = __expf(ev);
    den += ee;
    a0 = fmaf(ee, n4.x, a0);
    a1 = fmaf(ee, n4.y, a1);
  }
#pragma unroll
  for (int off = 8; off; off >>= 1) {
    den += __shfl_xor(den, off, 16);
    a0 += __shfl_xor(a0, off, 16);
    a1 += __shfl_xor(a1, off, 16);
  }
  if (l == 0) {
    float inv = 1.f / fmaxf(den, 1e-16f);
    float z0 = a0 * inv + b2[0];
    float z1 = a1 * inv + b2[1];
    float m = fmaxf(z0, z1);
    float lse = m + logf(__expf(z0 - m) + __expf(z1 - m));
    out[dn * 2 + 0] = z0 - lse;
    out[dn * 2 + 1] = z1 - lse;
  }
}

extern "C" void kernel_launch(void* const* d_in, const int* in_sizes, int n_in,
                              void* d_out, int out_size, void* d_ws,
                              size_t ws_size, hipStream_t stream) {
  const float* x   = (const float*)d_in[0];
  const int* esrc  = (const int*)d_in[1];
  const int* edst  = (const int*)d_in[2];
  const float* W1  = (const float*)d_in[3];
  const float* al1 = (const float*)d_in[4];
  const float* ar1 = (const float*)d_in[5];
  const float* b1  = (const float*)d_in[6];
  const float* W2  = (const float*)d_in[7];
  const float* al2 = (const float*)d_in[8];
  const float* ar2 = (const float*)d_in[9];
  const float* b2  = (const float*)d_in[10];
  float* out = (float*)d_out;

  size_t off = 0;
  auto alloc = [&](size_t bytes) {
    void* p = (char*)d_ws + off;
    off += (bytes + 255) & ~(size_t)255;
    return p;
  };
  unsigned char* feat8 = (unsigned char*)alloc((size_t)NN * 256);
  unsigned short* W1p  = (unsigned short*)alloc((size_t)16 * 8 * 64 * 8 * 2);
  unsigned short* walar = (unsigned short*)alloc((size_t)8 * 64 * 8 * 2);
  float* el1    = (float*)alloc((size_t)NN * 8 * 4);
  float* er1    = (float*)alloc((size_t)NN * 8 * 4);
  float4* node4 = (float4*)alloc((size_t)NN * 16);
  int* stage    = (int*)alloc((size_t)NBK * CAP * 4);
  int* hmat     = (int*)alloc((size_t)NBK * NPB * 4);
  unsigned short* csr = (unsigned short*)alloc((size_t)NBK * CAP * 2);
  int2* od      = (int2*)alloc((size_t)NN * 8);
  int* cur      = (int*)alloc((size_t)NBK * 4);

  k_hist2<<<NPB, 256, 0, stream>>>(edst, hmat, NE);
  k_cscan<<<NBK, NPB, 0, stream>>>(hmat, cur);
  k_part2<<<NPB, 256, 0, stream>>>(edst, esrc, hmat, stage, NE);
  k_build<<<NBK, 512, 0, stream>>>(stage, cur, od, csr, NN);

  k_packw<<<34, 256, 0, stream>>>(W1, al1, ar1, W1p, walar);
  k_gemm1m<<<(NN + 31) / 32, 256, 0, stream>>>(x, W1p, walar, feat8, el1,
                                               er1, NN);
  k_agg1<<<(NN + 3) / 4, 256, 0, stream>>>(feat8, el1, er1, od, csr, b1,
                                           W2, al2, ar2, node4, NN);
  k_agg2<<<(NN + 15) / 16, 256, 0, stream>>>(node4, od, csr, b2, out, NN);
}